// Round 1
// baseline (379.195 us; speedup 1.0000x reference)
//
#include <hip/hip_runtime.h>
#include <cstdint>
#include <cstddef>

// Problem constants (B,S,E,D from reference)
#define B_ 4
#define S_ 2048
#define E_ 1024
#define D_ 1024
#define MFLAT (B_*S_)   // 8192 rows flattened

typedef __attribute__((ext_vector_type(4))) float f32x4;
typedef __attribute__((ext_vector_type(8))) short short8;
typedef unsigned short u16;
typedef unsigned int   u32;

// ---------- helpers ----------
__device__ __forceinline__ u16 f2bf(float f) {
  u32 u = __float_as_uint(f);
  u = (u + 0x7fffu + ((u >> 16) & 1u)) >> 16;   // RNE
  return (u16)u;
}

__device__ __forceinline__ void gll16(const void* g, void* lds) {
  __builtin_amdgcn_global_load_lds(
      (const __attribute__((address_space(1))) void*)g,
      (__attribute__((address_space(3))) void*)lds, 16, 0, 0);
}

// ---------- shared 128x128 bf16 NT GEMM core ----------
// A: [.. , lda] row-major, K contiguous. B: [.., ldb] row-major, K contiguous
// (i.e. C[m][n] = sum_k A[m][k]*B[n][k]).  4 waves, each owns a 64x64 quadrant
// as a 4x4 grid of 16x16x32 MFMA fragments. LDS tiles linear [128][32] bf16,
// staged via global_load_lds width-16 (lane-linear layout matches).
__device__ __forceinline__ void gemm_core(
    const u16* __restrict__ Ag, int lda,
    const u16* __restrict__ Bg, int ldb,
    int ksteps, u16* As, u16* Bs, f32x4 acc[4][4])
{
  const int tid = threadIdx.x;
  const int w = tid >> 6;
  const int l = tid & 63;
  const int srow = l >> 2;          // staging row within 16-row chunk
  const int skb  = (l & 3) << 3;    // staging k-elem offset (8 bf16 = 16B)
  const int fr = l & 15;            // fragment row/col
  const int fk = (l >> 4) << 3;     // fragment k offset
  const int wr = (w >> 1) << 6;     // wave quadrant row
  const int wc = (w & 1) << 6;      // wave quadrant col
  const int c0 = w * 2, c1 = c0 + 1;

  const u16* a0 = Ag + (size_t)(c0*16 + srow)*lda + skb;
  const u16* a1 = Ag + (size_t)(c1*16 + srow)*lda + skb;
  const u16* b0 = Bg + (size_t)(c0*16 + srow)*ldb + skb;
  const u16* b1 = Bg + (size_t)(c1*16 + srow)*ldb + skb;

  for (int kt = 0; kt < ksteps; ++kt) {
    gll16(a0, As + c0*512);
    gll16(a1, As + c1*512);
    gll16(b0, Bs + c0*512);
    gll16(b1, Bs + c1*512);
    a0 += 32; a1 += 32; b0 += 32; b1 += 32;
    __syncthreads();                 // compiler drains vmcnt before barrier
    short8 af[4], bfr[4];
#pragma unroll
    for (int i = 0; i < 4; ++i)
      af[i] = *(const short8*)(As + ((wr + i*16 + fr) << 5) + fk);
#pragma unroll
    for (int j = 0; j < 4; ++j)
      bfr[j] = *(const short8*)(Bs + ((wc + j*16 + fr) << 5) + fk);
#pragma unroll
    for (int i = 0; i < 4; ++i)
#pragma unroll
      for (int j = 0; j < 4; ++j)
        acc[i][j] = __builtin_amdgcn_mfma_f32_16x16x32_bf16(af[i], bfr[j], acc[i][j], 0, 0, 0);
    __syncthreads();                 // protect LDS before next stage
  }
}

// ---------- fp32 -> bf16 convert ----------
__global__ __launch_bounds__(256) void cvt_kernel(const float* __restrict__ src,
                                                  u16* __restrict__ dst, int n4) {
  int idx = blockIdx.x * blockDim.x + threadIdx.x;
  int stride = gridDim.x * blockDim.x;
  for (int i = idx; i < n4; i += stride) {
    float4 f = ((const float4*)src)[i];
    ushort4 o;
    o.x = f2bf(f.x); o.y = f2bf(f.y); o.z = f2bf(f.z); o.w = f2bf(f.w);
    ((ushort4*)dst)[i] = o;
  }
}

// ---------- per-batch valid lengths from padding_mask ----------
// Handles both bool-as-bytes (1B) and bool-as-int32 (4B) harness layouts.
__global__ __launch_bounds__(256) void lengths_kernel(const void* __restrict__ mask,
                                                      int* __restrict__ lengths) {
  __shared__ int isbytes;
  const int t = threadIdx.x;
  if (t == 0) isbytes = 0;
  __syncthreads();
  const int* wi = (const int*)mask;
  int bad = 0;
  for (int idx = t; idx < (B_*S_)/4; idx += 256) {   // scan byte-sized footprint as ints
    int v = wi[idx];
    if (v != 0 && v != 1) bad = 1;
  }
  if (bad) atomicOr(&isbytes, 1);
  __syncthreads();
  const int isb = isbytes;
  const int w = t >> 6, l = t & 63;
  const unsigned char* mb = (const unsigned char*)mask;
  int cnt = 0;
  for (int j = l; j < S_; j += 64) {
    int val = isb ? (int)mb[(size_t)w*S_ + j] : wi[(size_t)w*S_ + j];
    cnt += (val == 0);
  }
#pragma unroll
  for (int off = 32; off >= 1; off >>= 1) cnt += __shfl_xor(cnt, off);
  if (l == 0) lengths[w] = cnt;   // zeros form the valid prefix (mask = pos>=len)
}

// ---------- QKV projection GEMM: C = X @ W^T + b, bf16 out ----------
__global__ __launch_bounds__(256) void proj_kernel(
    const u16* __restrict__ X, const u16* __restrict__ W,
    const float* __restrict__ bq, const float* __restrict__ bk, const float* __restrict__ bv,
    u16* __restrict__ q, u16* __restrict__ k, u16* __restrict__ v)
{
  __shared__ u16 As[4096], Bs[4096];
  const int nt = blockIdx.x, mt = blockIdx.y, z = blockIdx.z;
  const u16* Xz = X + (size_t)z * ((size_t)MFLAT * E_);
  const u16* Wz = W + (size_t)z * ((size_t)D_ * E_);
  f32x4 acc[4][4];
#pragma unroll
  for (int i = 0; i < 4; ++i)
#pragma unroll
    for (int j = 0; j < 4; ++j) acc[i][j] = (f32x4){0.f,0.f,0.f,0.f};
  gemm_core(Xz + (size_t)(mt*128)*E_, E_, Wz + (size_t)(nt*128)*E_, E_, E_/32, As, Bs, acc);

  const float* bias = (z == 0) ? bq : (z == 1) ? bk : bv;
  u16* out = (z == 0) ? q : (z == 1) ? k : v;
  const int tid = threadIdx.x, w = tid >> 6, l = tid & 63;
  const int wr = (w >> 1) << 6, wc = (w & 1) << 6;
  const int orow = mt*128 + wr + ((l >> 4) << 2);
  const int ocol = nt*128 + wc + (l & 15);
#pragma unroll
  for (int i = 0; i < 4; ++i)
#pragma unroll
    for (int j = 0; j < 4; ++j) {
      const int col = ocol + j*16;
      const float bcol = bias[col];
#pragma unroll
      for (int r = 0; r < 4; ++r) {
        const int row = orow + i*16 + r;
        out[(size_t)row*D_ + col] = f2bf(acc[i][j][r] + bcol);
      }
    }
}

// ---------- v [b][s][d] -> vT [b][d][s] ----------
__global__ __launch_bounds__(256) void transpose_kernel(
    const u16* __restrict__ v, u16* __restrict__ vT)
{
  __shared__ u16 tl[64][68];
  const int xt = blockIdx.x;   // d tile
  const int yt = blockIdx.y;   // s tile
  const int b  = blockIdx.z;
  const int t = threadIdx.x;
  const int r0 = t >> 4;
  const int c4 = (t & 15) << 2;
  const u16* src = v + ((size_t)b*S_ + yt*64)*D_ + xt*64;
#pragma unroll
  for (int rr = r0; rr < 64; rr += 16) {
    ushort4 u = *(const ushort4*)(src + (size_t)rr*D_ + c4);
    tl[rr][c4+0] = u.x; tl[rr][c4+1] = u.y; tl[rr][c4+2] = u.z; tl[rr][c4+3] = u.w;
  }
  __syncthreads();
  u16* dst = vT + ((size_t)b*D_ + xt*64)*S_ + yt*64;
#pragma unroll
  for (int rr = r0; rr < 64; rr += 16) {
    ushort4 u;
    u.x = tl[c4+0][rr]; u.y = tl[c4+1][rr]; u.z = tl[c4+2][rr]; u.w = tl[c4+3][rr];
    *(ushort4*)(dst + (size_t)rr*S_ + c4) = u;
  }
}

// ---------- QK^T (lower-triangle tiles only), scaled fp32 scores ----------
__global__ __launch_bounds__(256) void qk_kernel(
    const u16* __restrict__ q, const u16* __restrict__ k,
    const int* __restrict__ lengths, float* __restrict__ scores)
{
  const int tx = blockIdx.x, ty = blockIdx.y, b = blockIdx.z;
  if (tx > ty) return;                       // causal: key tile above diagonal
  const int len = lengths[b];
  if (tx * 128 >= len) return;               // fully padded key tile
  __shared__ u16 As[4096], Bs[4096];
  f32x4 acc[4][4];
#pragma unroll
  for (int i = 0; i < 4; ++i)
#pragma unroll
    for (int j = 0; j < 4; ++j) acc[i][j] = (f32x4){0.f,0.f,0.f,0.f};
  const u16* Aq = q + ((size_t)b*S_ + (size_t)ty*128) * D_;
  const u16* Bk = k + ((size_t)b*S_ + (size_t)tx*128) * D_;
  gemm_core(Aq, D_, Bk, D_, D_/32, As, Bs, acc);

  const int tid = threadIdx.x, w = tid >> 6, l = tid & 63;
  const int wr = (w >> 1) << 6, wc = (w & 1) << 6;
  const int orow = ty*128 + wr + ((l >> 4) << 2);
  const int ocol = tx*128 + wc + (l & 15);
  float* sb = scores + (size_t)b*S_*S_;
#pragma unroll
  for (int i = 0; i < 4; ++i)
#pragma unroll
    for (int j = 0; j < 4; ++j)
#pragma unroll
      for (int r = 0; r < 4; ++r)
        sb[(size_t)(orow + i*16 + r)*S_ + (ocol + j*16)] = acc[i][j][r] * 0.03125f; // 1/sqrt(1024)
}

// ---------- row softmax (exact fp32), bf16 P with zero fill ----------
__global__ __launch_bounds__(256) void softmax_kernel(
    const float* __restrict__ scores, const int* __restrict__ lengths,
    u16* __restrict__ P)
{
  const int i = blockIdx.x, b = blockIdx.y;
  const int len = lengths[b];
  const int kmax = min(i + 1, len);          // valid keys: [0, kmax)
  const float* row = scores + ((size_t)b*S_ + i)*S_;
  u16* prow = P + ((size_t)b*S_ + i)*S_;
  const int t = threadIdx.x;
  const int j0 = t * 8;
  float v[8];
  {
    float4 x0 = *(const float4*)(row + j0);
    float4 x1 = *(const float4*)(row + j0 + 4);
    v[0]=x0.x; v[1]=x0.y; v[2]=x0.z; v[3]=x0.w;
    v[4]=x1.x; v[5]=x1.y; v[6]=x1.z; v[7]=x1.w;
  }
  float m = -3.4e38f;
#pragma unroll
  for (int e = 0; e < 8; ++e) if (j0 + e < kmax) m = fmaxf(m, v[e]);
#pragma unroll
  for (int off = 32; off >= 1; off >>= 1) m = fmaxf(m, __shfl_xor(m, off));
  __shared__ float redm[4], reds[4];
  if ((t & 63) == 0) redm[t >> 6] = m;
  __syncthreads();
  m = fmaxf(fmaxf(redm[0], redm[1]), fmaxf(redm[2], redm[3]));
  float s = 0.f, ex[8];
#pragma unroll
  for (int e = 0; e < 8; ++e) {
    ex[e] = (j0 + e < kmax) ? __expf(v[e] - m) : 0.f;
    s += ex[e];
  }
#pragma unroll
  for (int off = 32; off >= 1; off >>= 1) s += __shfl_xor(s, off);
  if ((t & 63) == 0) reds[t >> 6] = s;
  __syncthreads();
  s = reds[0] + reds[1] + reds[2] + reds[3];
  const float inv = 1.0f / s;
  short8 o;
#pragma unroll
  for (int e = 0; e < 8; ++e) o[e] = (short)f2bf(ex[e] * inv);
  *(short8*)(prow + j0) = o;                 // zero beyond kmax -> PV needs no mask
}

// ---------- PV GEMM with causal K-cap, fp32 out ----------
__global__ __launch_bounds__(256) void pv_kernel(
    const u16* __restrict__ P, const u16* __restrict__ vT,
    const int* __restrict__ lengths, float* __restrict__ out)
{
  const int xt = blockIdx.x, ty = blockIdx.y, b = blockIdx.z;
  const int len = lengths[b];
  const int kend = min(ty*128 + 128, len);
  const int ksteps = (kend + 31) >> 5;       // >=1 since len>=1
  __shared__ u16 As[4096], Bs[4096];
  f32x4 acc[4][4];
#pragma unroll
  for (int i = 0; i < 4; ++i)
#pragma unroll
    for (int j = 0; j < 4; ++j) acc[i][j] = (f32x4){0.f,0.f,0.f,0.f};
  const u16* Ap = P  + ((size_t)b*S_ + (size_t)ty*128)*S_;
  const u16* Bv = vT + ((size_t)b*D_ + (size_t)xt*128)*S_;
  gemm_core(Ap, S_, Bv, S_, ksteps, As, Bs, acc);

  const int tid = threadIdx.x, w = tid >> 6, l = tid & 63;
  const int wr = (w >> 1) << 6, wc = (w & 1) << 6;
  const int orow = ty*128 + wr + ((l >> 4) << 2);
  const int ocol = xt*128 + wc + (l & 15);
  float* ob = out + (size_t)b*S_*D_;
#pragma unroll
  for (int i = 0; i < 4; ++i)
#pragma unroll
    for (int j = 0; j < 4; ++j)
#pragma unroll
      for (int r = 0; r < 4; ++r)
        ob[(size_t)(orow + i*16 + r)*D_ + (ocol + j*16)] = acc[i][j][r];
}

// ---------- launch ----------
extern "C" void kernel_launch(void* const* d_in, const int* in_sizes, int n_in,
                              void* d_out, int out_size, void* d_ws, size_t ws_size,
                              hipStream_t stream)
{
  const float* query = (const float*)d_in[0];
  const float* key_  = (const float*)d_in[1];
  const float* value = (const float*)d_in[2];
  const float* Wq = (const float*)d_in[3];
  const float* bq = (const float*)d_in[4];
  const float* Wk = (const float*)d_in[5];
  const float* bk = (const float*)d_in[6];
  const float* Wv = (const float*)d_in[7];
  const float* bv = (const float*)d_in[8];
  const void*  pmask = d_in[9];
  float* out = (float*)d_out;
  char* ws = (char*)d_ws;

  // workspace layout (bytes):
  //   [0,16)            lengths (int[4])
  //   [256, +50331648)  q,k bf16 [8192][1024] + vT bf16 [4][1024][2048]
  //   [50331904, +33554432)  P bf16 [4][2048][2048]  (also v-normal temp pre-softmax)
  //   [83886336, +67108864)  union: {X bf16 (50.3MB) + W bf16 (6.3MB)} then scores fp32
  // total: 150,995,200 B
  int* lengths = (int*)ws;
  u16* q   = (u16*)(ws + 256);
  u16* kk  = q  + (size_t)MFLAT * D_;
  u16* vT  = kk + (size_t)MFLAT * D_;
  u16* Pbuf = (u16*)(ws + 50331904ull);
  u16* vbuf = Pbuf;                       // v normal layout, dead before softmax
  char* scratch = ws + 83886336ull;
  u16* Xb = (u16*)scratch;
  u16* Wb = Xb + 3ull * MFLAT * E_;
  float* scores = (float*)scratch;        // aliases Xb/Wb after projections

  // P0: converts + lengths
  cvt_kernel<<<dim3(2048), 256, 0, stream>>>(query, Xb,                 (MFLAT*E_)/4);
  cvt_kernel<<<dim3(2048), 256, 0, stream>>>(key_,  Xb + (size_t)MFLAT*E_,   (MFLAT*E_)/4);
  cvt_kernel<<<dim3(2048), 256, 0, stream>>>(value, Xb + 2ull*MFLAT*E_, (MFLAT*E_)/4);
  cvt_kernel<<<dim3(256),  256, 0, stream>>>(Wq, Wb,                    (D_*E_)/4);
  cvt_kernel<<<dim3(256),  256, 0, stream>>>(Wk, Wb + (size_t)D_*E_,    (D_*E_)/4);
  cvt_kernel<<<dim3(256),  256, 0, stream>>>(Wv, Wb + 2ull*D_*E_,       (D_*E_)/4);
  lengths_kernel<<<dim3(1), 256, 0, stream>>>(pmask, lengths);

  // P1: projections (z = 0:q, 1:k, 2:v-normal into Pbuf region)
  proj_kernel<<<dim3(8, 64, 3), 256, 0, stream>>>(Xb, Wb, bq, bk, bv, q, kk, vbuf);

  // P1b: v -> vT
  transpose_kernel<<<dim3(16, 32, 4), 256, 0, stream>>>(vbuf, vT);

  // P2: QK^T (lower-triangle tiles), scores fp32 (overwrites Xb/Wb)
  qk_kernel<<<dim3(16, 16, 4), 256, 0, stream>>>(q, kk, lengths, scores);

  // P3: softmax -> bf16 P (overwrites vbuf)
  softmax_kernel<<<dim3(2048, 4), 256, 0, stream>>>(scores, lengths, Pbuf);

  // P4: PV -> out
  pv_kernel<<<dim3(8, 16, 4), 256, 0, stream>>>(Pbuf, vT, lengths, out);
}

// Round 2
// 373.203 us; speedup vs baseline: 1.0161x; 1.0161x over previous
//
#include <hip/hip_runtime.h>
#include <cstdint>
#include <cstddef>

// Problem constants (B,S,E,D from reference)
#define B_ 4
#define S_ 2048
#define E_ 1024
#define D_ 1024
#define MFLAT (B_*S_)   // 8192 rows flattened

typedef __attribute__((ext_vector_type(4))) float f32x4;
typedef __attribute__((ext_vector_type(8))) short short8;
typedef unsigned short u16;
typedef unsigned int   u32;

// ---------- helpers ----------
__device__ __forceinline__ u16 f2bf(float f) {
  u32 u = __float_as_uint(f);
  u = (u + 0x7fffu + ((u >> 16) & 1u)) >> 16;   // RNE
  return (u16)u;
}

__device__ __forceinline__ void gll16(const void* g, void* lds) {
  __builtin_amdgcn_global_load_lds(
      (const __attribute__((address_space(1))) void*)g,
      (__attribute__((address_space(3))) void*)lds, 16, 0, 0);
}

// Compiler-level memory fence around the raw HW barrier (s_barrier intrinsic is
// IntrNoMem in LLVM -> loads could otherwise migrate across it).
#define BARRIER() do { asm volatile("" ::: "memory"); \
                       __builtin_amdgcn_s_barrier();  \
                       asm volatile("" ::: "memory"); } while (0)

// =====================================================================
// 256x256 8-wave phase-interleaved NT GEMM core (T2+T3+T4+T5).
//   C[m][n] = sum_k A[m][k] * B[n][k], A/B bf16 row-major K-contiguous.
//   BK=64 K-tiles, 4 phases/tile, double-buffered 128 KiB LDS.
//   LDS: A [2buf][2half][128 rows][64 k] bf16 at 0; B same at 65536.
//   Swizzle: within a 128-B row, byte col ^= ((row&7)<<4)  (involution).
//   global_load_lds writes linearly -> global SOURCE is inverse-swizzled,
//   ds_read applies the same XOR (both-sides rule).
//   Prefetch: during tile t issue halves {A0,A1}(t+1) [free buffer] and
//   {B0,B1}(t+2) [current buffer, but B regions are past their last read
//   (phase 1) when issued at phases 2/3]. One s_waitcnt vmcnt(4) per tile.
//   Requires NT >= 2 (prologue stages 6 halves).
// =====================================================================
__device__ __forceinline__ void gemm256_core(
    const u16* __restrict__ Ag, int lda,
    const u16* __restrict__ Bg, int ldb,
    int NT, char* lds, f32x4 acc[8][4])
{
  const int tid = threadIdx.x;          // 0..511
  const int w  = tid >> 6;
  const int l  = tid & 63;
  const int wm = w >> 2;                // 0..1  -> A half / 128-row band
  const int wn = w & 3;                 // 0..3  -> 64-col band

  // staging: thread covers LDS bytes t*16 (+8192 for round 1) of a half-tile
  const int srow = tid >> 3;            // rows 0..63 (round 1 adds 64)
  const int scs  = ((tid & 7) << 4) ^ ((srow & 7) << 4);   // pre-swizzled src col bytes

  // fragment read geometry
  const int fr = l & 15;                // frag row (M or N)
  const int kq = l >> 4;                // k-quarter
  const int kcol0 = (kq << 4) ^ ((l & 7) << 4);
  const int kcol1 = ((kq << 4) + 64) ^ ((l & 7) << 4);
  const int aoff = wm * 16384 + fr * 128;
  const int boff = 65536 + (wn >> 1) * 16384 + (((wn & 1) * 64 + fr) * 128);

  const int nhalf = 4 * NT;

#define STAGE_HALF(h_) do {                                                        \
    const int h__ = (h_);                                                          \
    if (h__ < nhalf) {                                                             \
      const int T__ = h__ >> 2, r__ = h__ & 3, buf__ = T__ & 1;                    \
      const char* s0; char* d0; size_t rstep;                                      \
      if (r__ < 2) {                                                               \
        s0 = (const char*)Bg + ((((size_t)(r__*128 + srow)) * (size_t)ldb          \
                                 + (size_t)T__*64) << 1) + scs;                    \
        d0 = lds + 65536 + buf__*32768 + r__*16384 + (w << 10);                    \
        rstep = ((size_t)ldb) << 7;                                                \
      } else {                                                                     \
        s0 = (const char*)Ag + ((((size_t)((r__-2)*128 + srow)) * (size_t)lda      \
                                 + (size_t)T__*64) << 1) + scs;                    \
        d0 = lds + buf__*32768 + (r__-2)*16384 + (w << 10);                        \
        rstep = ((size_t)lda) << 7;                                                \
      }                                                                            \
      gll16(s0, d0);                                                               \
      gll16(s0 + rstep, d0 + 8192);                                                \
    }                                                                              \
  } while (0)

#define LDA_F(mf, kc) (*(const short8*)(lds + bufo + aoff + (mf)*2048 + (kc)))
#define LDB_F(nf, kc) (*(const short8*)(lds + bufo + boff + (nf)*2048 + (kc)))

#define WAIT_LGKM() do { asm volatile("s_waitcnt lgkmcnt(0)" ::: "memory"); \
                         __builtin_amdgcn_sched_barrier(0); } while (0)

#define MFMA_Q(jbase) do {                                                         \
    __builtin_amdgcn_s_setprio(1);                                                 \
    _Pragma("unroll")                                                              \
    for (int i = 0; i < 4; ++i) {                                                  \
      _Pragma("unroll")                                                            \
      for (int j = 0; j < 2; ++j) {                                                \
        acc[accm + i][(jbase) + j] = __builtin_amdgcn_mfma_f32_16x16x32_bf16(      \
            areg[i][0], breg[(jbase)+j][0], acc[accm + i][(jbase)+j], 0, 0, 0);    \
        acc[accm + i][(jbase) + j] = __builtin_amdgcn_mfma_f32_16x16x32_bf16(      \
            areg[i][1], breg[(jbase)+j][1], acc[accm + i][(jbase)+j], 0, 0, 0);    \
      }                                                                            \
    }                                                                              \
    __builtin_amdgcn_s_setprio(0);                                                 \
  } while (0)

  short8 areg[4][2], breg[4][2];

  // ---- prologue: stage tile0 fully + B halves of tile1; wait tile0 ----
  STAGE_HALF(0); STAGE_HALF(1); STAGE_HALF(2); STAGE_HALF(3);
  STAGE_HALF(4); STAGE_HALF(5);
  asm volatile("s_waitcnt vmcnt(4)" ::: "memory");   // halves 0..3 (tile 0) done
  BARRIER();

  for (int t = 0; t < NT; ++t) {
    const int bufo = (t & 1) << 15;
    const int hb = 4 * t + 6;

    // ---- phase 0: read A mf0-3 + B nf0-1 ; stage A0(t+1) ; MFMA Q(m0,n01)
    {
      int accm = 0;
#pragma unroll
      for (int i = 0; i < 4; ++i) { areg[i][0] = LDA_F(i, kcol0); areg[i][1] = LDA_F(i, kcol1); }
#pragma unroll
      for (int j = 0; j < 2; ++j) { breg[j][0] = LDB_F(j, kcol0); breg[j][1] = LDB_F(j, kcol1); }
      STAGE_HALF(hb + 0);
      BARRIER();
      WAIT_LGKM();
      MFMA_Q(0);
      BARRIER();
    }
    // ---- phase 1: read B nf2-3 ; stage A1(t+1) ; MFMA Q(m0,n23)
    {
      int accm = 0;
#pragma unroll
      for (int j = 2; j < 4; ++j) { breg[j][0] = LDB_F(j, kcol0); breg[j][1] = LDB_F(j, kcol1); }
      STAGE_HALF(hb + 1);
      BARRIER();
      WAIT_LGKM();
      MFMA_Q(2);
      BARRIER();
    }
    // ---- phase 2: read A mf4-7 ; stage B0(t+2) ; MFMA Q(m1,n01)
    {
      int accm = 4;
#pragma unroll
      for (int i = 0; i < 4; ++i) { areg[i][0] = LDA_F(4 + i, kcol0); areg[i][1] = LDA_F(4 + i, kcol1); }
      STAGE_HALF(hb + 2);
      BARRIER();
      WAIT_LGKM();
      MFMA_Q(0);
      BARRIER();
    }
    // ---- phase 3: no reads ; stage B1(t+2) ; MFMA Q(m1,n23) ; vmcnt(4)
    {
      int accm = 4;
      STAGE_HALF(hb + 3);
      BARRIER();
      WAIT_LGKM();
      MFMA_Q(2);
      // wait until only the 2 newest halves are in flight -> tile t+1 staged
      asm volatile("s_waitcnt vmcnt(4)" ::: "memory");
      BARRIER();
    }
  }
#undef STAGE_HALF
#undef LDA_F
#undef LDB_F
#undef WAIT_LGKM
#undef MFMA_Q
}

// ---------- legacy 128x128 core (kept for pv) ----------
__device__ __forceinline__ void gemm_core(
    const u16* __restrict__ Ag, int lda,
    const u16* __restrict__ Bg, int ldb,
    int ksteps, u16* As, u16* Bs, f32x4 acc[4][4])
{
  const int tid = threadIdx.x;
  const int w = tid >> 6;
  const int l = tid & 63;
  const int srow = l >> 2;
  const int skb  = (l & 3) << 3;
  const int fr = l & 15;
  const int fk = (l >> 4) << 3;
  const int wr = (w >> 1) << 6;
  const int wc = (w & 1) << 6;
  const int c0 = w * 2, c1 = c0 + 1;

  const u16* a0 = Ag + (size_t)(c0*16 + srow)*lda + skb;
  const u16* a1 = Ag + (size_t)(c1*16 + srow)*lda + skb;
  const u16* b0 = Bg + (size_t)(c0*16 + srow)*ldb + skb;
  const u16* b1 = Bg + (size_t)(c1*16 + srow)*ldb + skb;

  for (int kt = 0; kt < ksteps; ++kt) {
    gll16(a0, As + c0*512);
    gll16(a1, As + c1*512);
    gll16(b0, Bs + c0*512);
    gll16(b1, Bs + c1*512);
    a0 += 32; a1 += 32; b0 += 32; b1 += 32;
    __syncthreads();
    short8 af[4], bfr[4];
#pragma unroll
    for (int i = 0; i < 4; ++i)
      af[i] = *(const short8*)(As + ((wr + i*16 + fr) << 5) + fk);
#pragma unroll
    for (int j = 0; j < 4; ++j)
      bfr[j] = *(const short8*)(Bs + ((wc + j*16 + fr) << 5) + fk);
#pragma unroll
    for (int i = 0; i < 4; ++i)
#pragma unroll
      for (int j = 0; j < 4; ++j)
        acc[i][j] = __builtin_amdgcn_mfma_f32_16x16x32_bf16(af[i], bfr[j], acc[i][j], 0, 0, 0);
    __syncthreads();
  }
}

// ---------- fp32 -> bf16 convert ----------
__global__ __launch_bounds__(256) void cvt_kernel(const float* __restrict__ src,
                                                  u16* __restrict__ dst, int n4) {
  int idx = blockIdx.x * blockDim.x + threadIdx.x;
  int stride = gridDim.x * blockDim.x;
  for (int i = idx; i < n4; i += stride) {
    float4 f = ((const float4*)src)[i];
    ushort4 o;
    o.x = f2bf(f.x); o.y = f2bf(f.y); o.z = f2bf(f.z); o.w = f2bf(f.w);
    ((ushort4*)dst)[i] = o;
  }
}

// ---------- per-batch valid lengths from padding_mask ----------
__global__ __launch_bounds__(256) void lengths_kernel(const void* __restrict__ mask,
                                                      int* __restrict__ lengths) {
  __shared__ int isbytes;
  const int t = threadIdx.x;
  if (t == 0) isbytes = 0;
  __syncthreads();
  const int* wi = (const int*)mask;
  int bad = 0;
  for (int idx = t; idx < (B_*S_)/4; idx += 256) {
    int v = wi[idx];
    if (v != 0 && v != 1) bad = 1;
  }
  if (bad) atomicOr(&isbytes, 1);
  __syncthreads();
  const int isb = isbytes;
  const int w = t >> 6, l = t & 63;
  const unsigned char* mb = (const unsigned char*)mask;
  int cnt = 0;
  for (int j = l; j < S_; j += 64) {
    int val = isb ? (int)mb[(size_t)w*S_ + j] : wi[(size_t)w*S_ + j];
    cnt += (val == 0);
  }
#pragma unroll
  for (int off = 32; off >= 1; off >>= 1) cnt += __shfl_xor(cnt, off);
  if (l == 0) lengths[w] = cnt;
}

// ---------- QKV projection GEMM (256^2 core): C = X @ W^T + b, bf16 out ----------
__global__ __launch_bounds__(512, 2) void proj256_kernel(
    const u16* __restrict__ X, const u16* __restrict__ W,
    const float* __restrict__ bq, const float* __restrict__ bk, const float* __restrict__ bv,
    u16* __restrict__ q, u16* __restrict__ k, u16* __restrict__ v)
{
  extern __shared__ char lds[];
  const int nt = blockIdx.x, mt = blockIdx.y, z = blockIdx.z;
  const u16* Xz = X + (size_t)z * ((size_t)MFLAT * E_) + (size_t)(mt*256)*E_;
  const u16* Wz = W + (size_t)z * ((size_t)D_ * E_)    + (size_t)(nt*256)*E_;
  f32x4 acc[8][4];
#pragma unroll
  for (int i = 0; i < 8; ++i)
#pragma unroll
    for (int j = 0; j < 4; ++j) acc[i][j] = (f32x4){0.f,0.f,0.f,0.f};

  gemm256_core(Xz, E_, Wz, E_, E_/64, lds, acc);

  const float* bias = (z == 0) ? bq : (z == 1) ? bk : bv;
  u16* out = (z == 0) ? q : (z == 1) ? k : v;
  const int tid = threadIdx.x, w = tid >> 6, l = tid & 63;
  const int wm = w >> 2, wn = w & 3;
  const int fr = l & 15, kq = l >> 4;
  const int orow0 = mt*256 + wm*128 + kq*4;
  const int ocol0 = nt*256 + wn*64 + fr;
#pragma unroll
  for (int nf = 0; nf < 4; ++nf) {
    const int col = ocol0 + nf*16;
    const float bcol = bias[col];
#pragma unroll
    for (int mf = 0; mf < 8; ++mf)
#pragma unroll
      for (int r = 0; r < 4; ++r)
        out[(size_t)(orow0 + mf*16 + r)*D_ + col] = f2bf(acc[mf][nf][r] + bcol);
  }
}

// ---------- v [b][s][d] -> vT [b][d][s] ----------
__global__ __launch_bounds__(256) void transpose_kernel(
    const u16* __restrict__ v, u16* __restrict__ vT)
{
  __shared__ u16 tl[64][68];
  const int xt = blockIdx.x;
  const int yt = blockIdx.y;
  const int b  = blockIdx.z;
  const int t = threadIdx.x;
  const int r0 = t >> 4;
  const int c4 = (t & 15) << 2;
  const u16* src = v + ((size_t)b*S_ + yt*64)*D_ + xt*64;
#pragma unroll
  for (int rr = r0; rr < 64; rr += 16) {
    ushort4 u = *(const ushort4*)(src + (size_t)rr*D_ + c4);
    tl[rr][c4+0] = u.x; tl[rr][c4+1] = u.y; tl[rr][c4+2] = u.z; tl[rr][c4+3] = u.w;
  }
  __syncthreads();
  u16* dst = vT + ((size_t)b*D_ + xt*64)*S_ + yt*64;
#pragma unroll
  for (int rr = r0; rr < 64; rr += 16) {
    ushort4 u;
    u.x = tl[c4+0][rr]; u.y = tl[c4+1][rr]; u.z = tl[c4+2][rr]; u.w = tl[c4+3][rr];
    *(ushort4*)(dst + (size_t)rr*S_ + c4) = u;
  }
}

// ---------- QK^T (256^2 core, lower-triangle tiles), scaled fp32 scores ----------
__global__ __launch_bounds__(512, 2) void qk256_kernel(
    const u16* __restrict__ q, const u16* __restrict__ k,
    const int* __restrict__ lengths, float* __restrict__ scores)
{
  const int tx = blockIdx.x, ty = blockIdx.y, b = blockIdx.z;
  if (tx > ty) return;
  const int len = lengths[b];
  if (tx * 256 >= len) return;
  extern __shared__ char lds[];
  f32x4 acc[8][4];
#pragma unroll
  for (int i = 0; i < 8; ++i)
#pragma unroll
    for (int j = 0; j < 4; ++j) acc[i][j] = (f32x4){0.f,0.f,0.f,0.f};
  const u16* Aq = q + ((size_t)b*S_ + (size_t)ty*256) * D_;
  const u16* Bk = k + ((size_t)b*S_ + (size_t)tx*256) * D_;
  gemm256_core(Aq, D_, Bk, D_, D_/64, lds, acc);

  const int tid = threadIdx.x, w = tid >> 6, l = tid & 63;
  const int wm = w >> 2, wn = w & 3;
  const int fr = l & 15, kq = l >> 4;
  const int orow0 = ty*256 + wm*128 + kq*4;
  const int ocol0 = tx*256 + wn*64 + fr;
  float* sb = scores + (size_t)b*S_*S_;
#pragma unroll
  for (int mf = 0; mf < 8; ++mf)
#pragma unroll
    for (int nf = 0; nf < 4; ++nf)
#pragma unroll
      for (int r = 0; r < 4; ++r)
        sb[(size_t)(orow0 + mf*16 + r)*S_ + (ocol0 + nf*16)] = acc[mf][nf][r] * 0.03125f;
}

// ---------- row softmax (exact fp32), bf16 P with zero fill ----------
__global__ __launch_bounds__(256) void softmax_kernel(
    const float* __restrict__ scores, const int* __restrict__ lengths,
    u16* __restrict__ P)
{
  const int i = blockIdx.x, b = blockIdx.y;
  const int len = lengths[b];
  const int kmax = min(i + 1, len);
  const float* row = scores + ((size_t)b*S_ + i)*S_;
  u16* prow = P + ((size_t)b*S_ + i)*S_;
  const int t = threadIdx.x;
  const int j0 = t * 8;
  float v[8];
  {
    float4 x0 = *(const float4*)(row + j0);
    float4 x1 = *(const float4*)(row + j0 + 4);
    v[0]=x0.x; v[1]=x0.y; v[2]=x0.z; v[3]=x0.w;
    v[4]=x1.x; v[5]=x1.y; v[6]=x1.z; v[7]=x1.w;
  }
  float m = -3.4e38f;
#pragma unroll
  for (int e = 0; e < 8; ++e) if (j0 + e < kmax) m = fmaxf(m, v[e]);
#pragma unroll
  for (int off = 32; off >= 1; off >>= 1) m = fmaxf(m, __shfl_xor(m, off));
  __shared__ float redm[4], reds[4];
  if ((t & 63) == 0) redm[t >> 6] = m;
  __syncthreads();
  m = fmaxf(fmaxf(redm[0], redm[1]), fmaxf(redm[2], redm[3]));
  float s = 0.f, ex[8];
#pragma unroll
  for (int e = 0; e < 8; ++e) {
    ex[e] = (j0 + e < kmax) ? __expf(v[e] - m) : 0.f;
    s += ex[e];
  }
#pragma unroll
  for (int off = 32; off >= 1; off >>= 1) s += __shfl_xor(s, off);
  if ((t & 63) == 0) reds[t >> 6] = s;
  __syncthreads();
  s = reds[0] + reds[1] + reds[2] + reds[3];
  const float inv = 1.0f / s;
  short8 o;
#pragma unroll
  for (int e = 0; e < 8; ++e) o[e] = (short)f2bf(ex[e] * inv);
  *(short8*)(prow + j0) = o;
}

// ---------- PV GEMM with causal K-cap (legacy 128^2 core), fp32 out ----------
__global__ __launch_bounds__(256) void pv_kernel(
    const u16* __restrict__ P, const u16* __restrict__ vT,
    const int* __restrict__ lengths, float* __restrict__ out)
{
  const int xt = blockIdx.x, ty = blockIdx.y, b = blockIdx.z;
  const int len = lengths[b];
  const int kend = min(ty*128 + 128, len);
  const int ksteps = (kend + 31) >> 5;
  __shared__ u16 As[4096], Bs[4096];
  f32x4 acc[4][4];
#pragma unroll
  for (int i = 0; i < 4; ++i)
#pragma unroll
    for (int j = 0; j < 4; ++j) acc[i][j] = (f32x4){0.f,0.f,0.f,0.f};
  const u16* Ap = P  + ((size_t)b*S_ + (size_t)ty*128)*S_;
  const u16* Bv = vT + ((size_t)b*D_ + (size_t)xt*128)*S_;
  gemm_core(Ap, S_, Bv, S_, ksteps, As, Bs, acc);

  const int tid = threadIdx.x, w = tid >> 6, l = tid & 63;
  const int wr = (w >> 1) << 6, wc = (w & 1) << 6;
  const int orow = ty*128 + wr + ((l >> 4) << 2);
  const int ocol = xt*128 + wc + (l & 15);
  float* ob = out + (size_t)b*S_*D_;
#pragma unroll
  for (int i = 0; i < 4; ++i)
#pragma unroll
    for (int j = 0; j < 4; ++j)
#pragma unroll
      for (int r = 0; r < 4; ++r)
        ob[(size_t)(orow + i*16 + r)*D_ + (ocol + j*16)] = acc[i][j][r];
}

// ---------- launch ----------
extern "C" void kernel_launch(void* const* d_in, const int* in_sizes, int n_in,
                              void* d_out, int out_size, void* d_ws, size_t ws_size,
                              hipStream_t stream)
{
  const float* query = (const float*)d_in[0];
  const float* key_  = (const float*)d_in[1];
  const float* value = (const float*)d_in[2];
  const float* Wq = (const float*)d_in[3];
  const float* bq = (const float*)d_in[4];
  const float* Wk = (const float*)d_in[5];
  const float* bk = (const float*)d_in[6];
  const float* Wv = (const float*)d_in[7];
  const float* bv = (const float*)d_in[8];
  const void*  pmask = d_in[9];
  float* out = (float*)d_out;
  char* ws = (char*)d_ws;

  // allow 128 KiB dynamic LDS for the 256^2-core kernels (idempotent)
  (void)hipFuncSetAttribute((const void*)proj256_kernel,
                            hipFuncAttributeMaxDynamicSharedMemorySize, 131072);
  (void)hipFuncSetAttribute((const void*)qk256_kernel,
                            hipFuncAttributeMaxDynamicSharedMemorySize, 131072);

  // workspace layout (bytes):
  //   [0,16)            lengths (int[4])
  //   [256, +50331648)  q,k bf16 [8192][1024] + vT bf16 [4][1024][2048]
  //   [50331904, +33554432)  P bf16 [4][2048][2048]  (also v-normal temp pre-softmax)
  //   [83886336, +67108864)  union: {X bf16 (50.3MB) + W bf16 (6.3MB)} then scores fp32
  int* lengths = (int*)ws;
  u16* q   = (u16*)(ws + 256);
  u16* kk  = q  + (size_t)MFLAT * D_;
  u16* vT  = kk + (size_t)MFLAT * D_;
  u16* Pbuf = (u16*)(ws + 50331904ull);
  u16* vbuf = Pbuf;
  char* scratch = ws + 83886336ull;
  u16* Xb = (u16*)scratch;
  u16* Wb = Xb + 3ull * MFLAT * E_;
  float* scores = (float*)scratch;

  // P0: converts + lengths
  cvt_kernel<<<dim3(2048), 256, 0, stream>>>(query, Xb,                 (MFLAT*E_)/4);
  cvt_kernel<<<dim3(2048), 256, 0, stream>>>(key_,  Xb + (size_t)MFLAT*E_,   (MFLAT*E_)/4);
  cvt_kernel<<<dim3(2048), 256, 0, stream>>>(value, Xb + 2ull*MFLAT*E_, (MFLAT*E_)/4);
  cvt_kernel<<<dim3(256),  256, 0, stream>>>(Wq, Wb,                    (D_*E_)/4);
  cvt_kernel<<<dim3(256),  256, 0, stream>>>(Wk, Wb + (size_t)D_*E_,    (D_*E_)/4);
  cvt_kernel<<<dim3(256),  256, 0, stream>>>(Wv, Wb + 2ull*D_*E_,       (D_*E_)/4);
  lengths_kernel<<<dim3(1), 256, 0, stream>>>(pmask, lengths);

  // P1: projections (z = 0:q, 1:k, 2:v-normal into Pbuf region)
  proj256_kernel<<<dim3(4, 32, 3), 512, 131072, stream>>>(Xb, Wb, bq, bk, bv, q, kk, vbuf);

  // P1b: v -> vT
  transpose_kernel<<<dim3(16, 32, 4), 256, 0, stream>>>(vbuf, vT);

  // P2: QK^T (lower-triangle 256-tiles), scores fp32 (overwrites Xb/Wb)
  qk256_kernel<<<dim3(8, 8, 4), 512, 131072, stream>>>(q, kk, lengths, scores);

  // P3: softmax -> bf16 P (overwrites vbuf)
  softmax_kernel<<<dim3(2048, 4), 256, 0, stream>>>(scores, lengths, Pbuf);

  // P4: PV -> out
  pv_kernel<<<dim3(8, 16, 4), 256, 0, stream>>>(Pbuf, vT, lengths, out);
}

// Round 4
// 355.072 us; speedup vs baseline: 1.0679x; 1.0511x over previous
//
#include <hip/hip_runtime.h>
#include <cstdint>
#include <cstddef>

// Problem constants (B,S,E,D from reference)
#define B_ 4
#define S_ 2048
#define E_ 1024
#define D_ 1024
#define MFLAT (B_*S_)   // 8192 rows flattened

typedef __attribute__((ext_vector_type(4))) float f32x4;
typedef __attribute__((ext_vector_type(8))) short short8;
typedef unsigned short u16;
typedef unsigned int   u32;

// ---------- helpers ----------
__device__ __forceinline__ u16 f2bf(float f) {
  u32 u = __float_as_uint(f);
  u = (u + 0x7fffu + ((u >> 16) & 1u)) >> 16;   // RNE
  return (u16)u;
}

__device__ __forceinline__ void gll16(const void* g, void* lds) {
  __builtin_amdgcn_global_load_lds(
      (const __attribute__((address_space(1))) void*)g,
      (__attribute__((address_space(3))) void*)lds, 16, 0, 0);
}

// Compiler-level memory fence around the raw HW barrier.
#define BARRIER() do { asm volatile("" ::: "memory"); \
                       __builtin_amdgcn_s_barrier();  \
                       asm volatile("" ::: "memory"); } while (0)

// =====================================================================
// 256x256 8-wave phase-interleaved NT GEMM core (T2+T3+T4+T5).
//   C[m][n] = sum_k A[m][k] * B[n][k], A/B bf16 row-major K-contiguous.
//   BK=64 K-tiles, 4 phases/tile, double-buffered 128 KiB LDS.
//   Swizzle: byte col ^= ((row&7)<<4); inverse-swizzled global SOURCE +
//   swizzled ds_read (both-sides rule; conflicts measured 0 in R2).
//   Counted vmcnt(4) once per tile (never 0 in the loop).
//   R3 fix: no sched_barrier(0) — m141 showed order-pinning caps at
//   ~510-550 TF; compiler ds_reads carry their own MFMA deps.
// =====================================================================
__device__ __forceinline__ void gemm256_core(
    const u16* __restrict__ Ag, int lda,
    const u16* __restrict__ Bg, int ldb,
    int NT, char* lds, f32x4 acc[8][4])
{
  const int tid = threadIdx.x;          // 0..511
  const int w  = tid >> 6;
  const int l  = tid & 63;
  const int wm = w >> 2;                // 0..1  -> 128-row band of C
  const int wn = w & 3;                 // 0..3  -> 64-col band of C

  // staging geometry
  const int srow = tid >> 3;            // rows 0..63 (second gll adds 64)
  const int scs  = ((tid & 7) << 4) ^ ((srow & 7) << 4);   // pre-swizzled src col bytes

  // fragment read geometry
  const int fr = l & 15;
  const int kq = l >> 4;
  const int kcol0 = (kq << 4) ^ ((l & 7) << 4);
  const int kcol1 = ((kq << 4) + 64) ^ ((l & 7) << 4);
  const int aoff = wm * 16384 + fr * 128;
  const int boff = 65536 + (wn >> 1) * 16384 + (((wn & 1) * 64 + fr) * 128);

  const int nhalf = 4 * NT;

#define STAGE_HALF(h_) do {                                                        \
    const int h__ = (h_);                                                          \
    if (h__ < nhalf) {                                                             \
      const int T__ = h__ >> 2, r__ = h__ & 3, buf__ = T__ & 1;                    \
      const char* s0; char* d0; size_t rstep;                                      \
      if (r__ < 2) {                                                               \
        s0 = (const char*)Bg + ((((size_t)(r__*128 + srow)) * (size_t)ldb          \
                                 + (size_t)T__*64) << 1) + scs;                    \
        d0 = lds + 65536 + buf__*32768 + r__*16384 + (w << 10);                    \
        rstep = ((size_t)ldb) << 7;                                                \
      } else {                                                                     \
        s0 = (const char*)Ag + ((((size_t)((r__-2)*128 + srow)) * (size_t)lda      \
                                 + (size_t)T__*64) << 1) + scs;                    \
        d0 = lds + buf__*32768 + (r__-2)*16384 + (w << 10);                        \
        rstep = ((size_t)lda) << 7;                                                \
      }                                                                            \
      gll16(s0, d0);                                                               \
      gll16(s0 + rstep, d0 + 8192);                                                \
    }                                                                              \
  } while (0)

#define LDA_F(mf, kc) (*(const short8*)(lds + bufo + aoff + (mf)*2048 + (kc)))
#define LDB_F(nf, kc) (*(const short8*)(lds + bufo + boff + (nf)*2048 + (kc)))

// asm lgkmcnt(0) only (per m201 template); NO sched_barrier(0).
#define WAIT_LGKM() asm volatile("s_waitcnt lgkmcnt(0)" ::: "memory")

#define MFMA_Q(jbase) do {                                                         \
    __builtin_amdgcn_s_setprio(1);                                                 \
    _Pragma("unroll")                                                              \
    for (int i = 0; i < 4; ++i) {                                                  \
      _Pragma("unroll")                                                            \
      for (int j = 0; j < 2; ++j) {                                                \
        acc[accm + i][(jbase) + j] = __builtin_amdgcn_mfma_f32_16x16x32_bf16(      \
            areg[i][0], breg[(jbase)+j][0], acc[accm + i][(jbase)+j], 0, 0, 0);    \
        acc[accm + i][(jbase) + j] = __builtin_amdgcn_mfma_f32_16x16x32_bf16(      \
            areg[i][1], breg[(jbase)+j][1], acc[accm + i][(jbase)+j], 0, 0, 0);    \
      }                                                                            \
    }                                                                              \
    __builtin_amdgcn_s_setprio(0);                                                 \
  } while (0)

  short8 areg[4][2], breg[4][2];

  // ---- prologue: stage tile0 fully + B halves of tile1; wait tile0 ----
  STAGE_HALF(0); STAGE_HALF(1); STAGE_HALF(2); STAGE_HALF(3);
  STAGE_HALF(4); STAGE_HALF(5);
  asm volatile("s_waitcnt vmcnt(4)" ::: "memory");   // tile 0 resident
  BARRIER();

  for (int t = 0; t < NT; ++t) {
    const int bufo = (t & 1) << 15;
    const int hb = 4 * t + 6;

    // phase 0: read A mf0-3 + B nf0-1 ; stage A0(t+1) ; MFMA (m0,n01)
    {
      int accm = 0;
#pragma unroll
      for (int i = 0; i < 4; ++i) { areg[i][0] = LDA_F(i, kcol0); areg[i][1] = LDA_F(i, kcol1); }
#pragma unroll
      for (int j = 0; j < 2; ++j) { breg[j][0] = LDB_F(j, kcol0); breg[j][1] = LDB_F(j, kcol1); }
      STAGE_HALF(hb + 0);
      BARRIER();
      WAIT_LGKM();
      MFMA_Q(0);
      BARRIER();
    }
    // phase 1: read B nf2-3 ; stage A1(t+1) ; MFMA (m0,n23)
    {
      int accm = 0;
#pragma unroll
      for (int j = 2; j < 4; ++j) { breg[j][0] = LDB_F(j, kcol0); breg[j][1] = LDB_F(j, kcol1); }
      STAGE_HALF(hb + 1);
      BARRIER();
      WAIT_LGKM();
      MFMA_Q(2);
      BARRIER();
    }
    // phase 2: read A mf4-7 ; stage B0(t+2) ; MFMA (m1,n01)
    {
      int accm = 4;
#pragma unroll
      for (int i = 0; i < 4; ++i) { areg[i][0] = LDA_F(4 + i, kcol0); areg[i][1] = LDA_F(4 + i, kcol1); }
      STAGE_HALF(hb + 2);
      BARRIER();
      WAIT_LGKM();
      MFMA_Q(0);
      BARRIER();
    }
    // phase 3: stage B1(t+2) ; MFMA (m1,n23) ; counted vmcnt
    {
      int accm = 4;
      STAGE_HALF(hb + 3);
      BARRIER();
      WAIT_LGKM();
      MFMA_Q(2);
      asm volatile("s_waitcnt vmcnt(4)" ::: "memory");  // tile t+1 resident
      BARRIER();
    }
  }
#undef STAGE_HALF
#undef LDA_F
#undef LDB_F
#undef WAIT_LGKM
#undef MFMA_Q
}

// ---------- legacy 128x128 core (kept for pv) ----------
__device__ __forceinline__ void gemm_core(
    const u16* __restrict__ Ag, int lda,
    const u16* __restrict__ Bg, int ldb,
    int ksteps, u16* As, u16* Bs, f32x4 acc[4][4])
{
  const int tid = threadIdx.x;
  const int w = tid >> 6;
  const int l = tid & 63;
  const int srow = l >> 2;
  const int skb  = (l & 3) << 3;
  const int fr = l & 15;
  const int fk = (l >> 4) << 3;
  const int wr = (w >> 1) << 6;
  const int wc = (w & 1) << 6;
  const int c0 = w * 2, c1 = c0 + 1;

  const u16* a0 = Ag + (size_t)(c0*16 + srow)*lda + skb;
  const u16* a1 = Ag + (size_t)(c1*16 + srow)*lda + skb;
  const u16* b0 = Bg + (size_t)(c0*16 + srow)*ldb + skb;
  const u16* b1 = Bg + (size_t)(c1*16 + srow)*ldb + skb;

  for (int kt = 0; kt < ksteps; ++kt) {
    gll16(a0, As + c0*512);
    gll16(a1, As + c1*512);
    gll16(b0, Bs + c0*512);
    gll16(b1, Bs + c1*512);
    a0 += 32; a1 += 32; b0 += 32; b1 += 32;
    __syncthreads();
    short8 af[4], bfr[4];
#pragma unroll
    for (int i = 0; i < 4; ++i)
      af[i] = *(const short8*)(As + ((wr + i*16 + fr) << 5) + fk);
#pragma unroll
    for (int j = 0; j < 4; ++j)
      bfr[j] = *(const short8*)(Bs + ((wc + j*16 + fr) << 5) + fk);
#pragma unroll
    for (int i = 0; i < 4; ++i)
#pragma unroll
      for (int j = 0; j < 4; ++j)
        acc[i][j] = __builtin_amdgcn_mfma_f32_16x16x32_bf16(af[i], bfr[j], acc[i][j], 0, 0, 0);
    __syncthreads();
  }
}

// ---------- fp32 -> bf16 convert, 3 equal segments in one launch ----------
__global__ __launch_bounds__(256) void cvt3_kernel(
    const float* __restrict__ s0, const float* __restrict__ s1,
    const float* __restrict__ s2, u16* __restrict__ dst, int segn4)
{
  int idx = blockIdx.x * blockDim.x + threadIdx.x;
  int stride = gridDim.x * blockDim.x;
  const int total = 3 * segn4;
  for (int i = idx; i < total; i += stride) {
    int s = i / segn4;
    int off = i - s * segn4;
    const float4* sp = (s == 0) ? (const float4*)s0 : (s == 1) ? (const float4*)s1 : (const float4*)s2;
    float4 f = sp[off];
    ushort4 o;
    o.x = f2bf(f.x); o.y = f2bf(f.y); o.z = f2bf(f.z); o.w = f2bf(f.w);
    ((ushort4*)dst)[i] = o;
  }
}

// ---------- per-batch valid lengths from padding_mask ----------
__global__ __launch_bounds__(256) void lengths_kernel(const void* __restrict__ mask,
                                                      int* __restrict__ lengths) {
  __shared__ int isbytes;
  const int t = threadIdx.x;
  if (t == 0) isbytes = 0;
  __syncthreads();
  const int* wi = (const int*)mask;
  int bad = 0;
  for (int idx = t; idx < (B_*S_)/4; idx += 256) {
    int v = wi[idx];
    if (v != 0 && v != 1) bad = 1;
  }
  if (bad) atomicOr(&isbytes, 1);
  __syncthreads();
  const int isb = isbytes;
  const int w = t >> 6, l = t & 63;
  const unsigned char* mb = (const unsigned char*)mask;
  int cnt = 0;
  for (int j = l; j < S_; j += 64) {
    int val = isb ? (int)mb[(size_t)w*S_ + j] : wi[(size_t)w*S_ + j];
    cnt += (val == 0);
  }
#pragma unroll
  for (int off = 32; off >= 1; off >>= 1) cnt += __shfl_xor(cnt, off);
  if (l == 0) lengths[w] = cnt;
}

// ---------- QKV projection GEMM (256^2 core): C = X @ W^T + b, bf16 out ----------
// 1D grid of 384 blocks, XCD-bijective swizzle (384 = 8 * 48).
__global__ __launch_bounds__(512, 2) void proj256_kernel(
    const u16* __restrict__ X, const u16* __restrict__ W,
    const float* __restrict__ bq, const float* __restrict__ bk, const float* __restrict__ bv,
    u16* __restrict__ q, u16* __restrict__ k, u16* __restrict__ v)
{
  extern __shared__ char lds[];
  const int bid = blockIdx.x;
  const int wg = (bid & 7) * 48 + (bid >> 3);   // XCD-contiguous chunks
  const int z  = wg >> 7;                        // 128 tiles per z
  const int rem = wg & 127;
  const int nt = rem >> 5;                       // 4 col tiles
  const int mt = rem & 31;                       // 32 row tiles (consecutive share W panel)

  const u16* Xz = X + (size_t)z * ((size_t)MFLAT * E_) + (size_t)(mt*256)*E_;
  const u16* Wz = W + (size_t)z * ((size_t)D_ * E_)    + (size_t)(nt*256)*E_;
  f32x4 acc[8][4];
#pragma unroll
  for (int i = 0; i < 8; ++i)
#pragma unroll
    for (int j = 0; j < 4; ++j) acc[i][j] = (f32x4){0.f,0.f,0.f,0.f};

  gemm256_core(Xz, E_, Wz, E_, E_/64, lds, acc);

  const float* bias = (z == 0) ? bq : (z == 1) ? bk : bv;
  u16* out = (z == 0) ? q : (z == 1) ? k : v;
  const int tid = threadIdx.x, w = tid >> 6, l = tid & 63;
  const int wm = w >> 2, wn = w & 3;
  const int fr = l & 15, kq = l >> 4;
  const int orow0 = mt*256 + wm*128 + kq*4;
  const int ocol0 = nt*256 + wn*64 + fr;
#pragma unroll
  for (int nf = 0; nf < 4; ++nf) {
    const int col = ocol0 + nf*16;
    const float bcol = bias[col];
#pragma unroll
    for (int mf = 0; mf < 8; ++mf)
#pragma unroll
      for (int r = 0; r < 4; ++r)
        out[(size_t)(orow0 + mf*16 + r)*D_ + col] = f2bf(acc[mf][nf][r] + bcol);
  }
}

// ---------- v [b][s][d] -> vT [b][d][s] ----------
__global__ __launch_bounds__(256) void transpose_kernel(
    const u16* __restrict__ v, u16* __restrict__ vT)
{
  __shared__ u16 tl[64][68];
  const int xt = blockIdx.x;
  const int yt = blockIdx.y;
  const int b  = blockIdx.z;
  const int t = threadIdx.x;
  const int r0 = t >> 4;
  const int c4 = (t & 15) << 2;
  const u16* src = v + ((size_t)b*S_ + yt*64)*D_ + xt*64;
#pragma unroll
  for (int rr = r0; rr < 64; rr += 16) {
    ushort4 u = *(const ushort4*)(src + (size_t)rr*D_ + c4);
    tl[rr][c4+0] = u.x; tl[rr][c4+1] = u.y; tl[rr][c4+2] = u.z; tl[rr][c4+3] = u.w;
  }
  __syncthreads();
  u16* dst = vT + ((size_t)b*D_ + xt*64)*S_ + yt*64;
#pragma unroll
  for (int rr = r0; rr < 64; rr += 16) {
    ushort4 u;
    u.x = tl[c4+0][rr]; u.y = tl[c4+1][rr]; u.z = tl[c4+2][rr]; u.w = tl[c4+3][rr];
    *(ushort4*)(dst + (size_t)rr*S_ + c4) = u;
  }
}

// ---------- QK^T (256^2 core), only valid lower-triangle tiles ----------
// 144 blocks (4 b x 36 triangle tiles), XCD-bijective (144 = 8 * 18).
__global__ __launch_bounds__(512, 2) void qk256_kernel(
    const u16* __restrict__ q, const u16* __restrict__ k,
    const int* __restrict__ lengths, float* __restrict__ scores)
{
  const int bid = blockIdx.x;
  const int wg = (bid & 7) * 18 + (bid >> 3);
  const int b = wg / 36;
  const int r = wg - b * 36;
  int ty = (int)((sqrtf(8.0f * (float)r + 1.0f) - 1.0f) * 0.5f);
  while ((ty + 1) * (ty + 2) / 2 <= r) ++ty;
  while (ty * (ty + 1) / 2 > r) --ty;
  const int tx = r - ty * (ty + 1) / 2;

  const int len = lengths[b];
  if (tx * 256 >= len) return;
  extern __shared__ char lds[];
  f32x4 acc[8][4];
#pragma unroll
  for (int i = 0; i < 8; ++i)
#pragma unroll
    for (int j = 0; j < 4; ++j) acc[i][j] = (f32x4){0.f,0.f,0.f,0.f};
  const u16* Aq = q + ((size_t)b*S_ + (size_t)ty*256) * D_;
  const u16* Bk = k + ((size_t)b*S_ + (size_t)tx*256) * D_;
  gemm256_core(Aq, D_, Bk, D_, D_/64, lds, acc);

  const int tid = threadIdx.x, w = tid >> 6, l = tid & 63;
  const int wm = w >> 2, wn = w & 3;
  const int fr = l & 15, kq = l >> 4;
  const int orow0 = ty*256 + wm*128 + kq*4;
  const int ocol0 = tx*256 + wn*64 + fr;
  float* sb = scores + (size_t)b*S_*S_;
#pragma unroll
  for (int mf = 0; mf < 8; ++mf)
#pragma unroll
    for (int nf = 0; nf < 4; ++nf)
#pragma unroll
      for (int r2 = 0; r2 < 4; ++r2)
        sb[(size_t)(orow0 + mf*16 + r2)*S_ + (ocol0 + nf*16)] = acc[mf][nf][r2] * 0.03125f;
}

// ---------- row softmax (exact fp32), bf16 P with zero fill ----------
__global__ __launch_bounds__(256) void softmax_kernel(
    const float* __restrict__ scores, const int* __restrict__ lengths,
    u16* __restrict__ P)
{
  const int i = blockIdx.x, b = blockIdx.y;
  const int len = lengths[b];
  const int kmax = min(i + 1, len);
  const float* row = scores + ((size_t)b*S_ + i)*S_;
  u16* prow = P + ((size_t)b*S_ + i)*S_;
  const int t = threadIdx.x;
  const int j0 = t * 8;
  float v[8];
  {
    float4 x0 = *(const float4*)(row + j0);
    float4 x1 = *(const float4*)(row + j0 + 4);
    v[0]=x0.x; v[1]=x0.y; v[2]=x0.z; v[3]=x0.w;
    v[4]=x1.x; v[5]=x1.y; v[6]=x1.z; v[7]=x1.w;
  }
  float m = -3.4e38f;
#pragma unroll
  for (int e = 0; e < 8; ++e) if (j0 + e < kmax) m = fmaxf(m, v[e]);
#pragma unroll
  for (int off = 32; off >= 1; off >>= 1) m = fmaxf(m, __shfl_xor(m, off));
  __shared__ float redm[4], reds[4];
  if ((t & 63) == 0) redm[t >> 6] = m;
  __syncthreads();
  m = fmaxf(fmaxf(redm[0], redm[1]), fmaxf(redm[2], redm[3]));
  float s = 0.f, ex[8];
#pragma unroll
  for (int e = 0; e < 8; ++e) {
    ex[e] = (j0 + e < kmax) ? __expf(v[e] - m) : 0.f;
    s += ex[e];
  }
#pragma unroll
  for (int off = 32; off >= 1; off >>= 1) s += __shfl_xor(s, off);
  if ((t & 63) == 0) reds[t >> 6] = s;
  __syncthreads();
  s = reds[0] + reds[1] + reds[2] + reds[3];
  const float inv = 1.0f / s;
  short8 o;
#pragma unroll
  for (int e = 0; e < 8; ++e) o[e] = (short)f2bf(ex[e] * inv);
  *(short8*)(prow + j0) = o;
}

// ---------- PV GEMM with causal K-cap (legacy 128^2 core), fp32 out ----------
__global__ __launch_bounds__(256) void pv_kernel(
    const u16* __restrict__ P, const u16* __restrict__ vT,
    const int* __restrict__ lengths, float* __restrict__ out)
{
  const int xt = blockIdx.x, ty = blockIdx.y, b = blockIdx.z;
  const int len = lengths[b];
  const int kend = min(ty*128 + 128, len);
  const int ksteps = (kend + 31) >> 5;
  __shared__ u16 As[4096], Bs[4096];
  f32x4 acc[4][4];
#pragma unroll
  for (int i = 0; i < 4; ++i)
#pragma unroll
    for (int j = 0; j < 4; ++j) acc[i][j] = (f32x4){0.f,0.f,0.f,0.f};
  const u16* Ap = P  + ((size_t)b*S_ + (size_t)ty*128)*S_;
  const u16* Bv = vT + ((size_t)b*D_ + (size_t)xt*128)*S_;
  gemm_core(Ap, S_, Bv, S_, ksteps, As, Bs, acc);

  const int tid = threadIdx.x, w = tid >> 6, l = tid & 63;
  const int wr = (w >> 1) << 6, wc = (w & 1) << 6;
  const int orow = ty*128 + wr + ((l >> 4) << 2);
  const int ocol = xt*128 + wc + (l & 15);
  float* ob = out + (size_t)b*S_*D_;
#pragma unroll
  for (int i = 0; i < 4; ++i)
#pragma unroll
    for (int j = 0; j < 4; ++j)
#pragma unroll
      for (int r = 0; r < 4; ++r)
        ob[(size_t)(orow + i*16 + r)*D_ + (ocol + j*16)] = acc[i][j][r];
}

// ---------- launch ----------
extern "C" void kernel_launch(void* const* d_in, const int* in_sizes, int n_in,
                              void* d_out, int out_size, void* d_ws, size_t ws_size,
                              hipStream_t stream)
{
  const float* query = (const float*)d_in[0];
  const float* key_  = (const float*)d_in[1];
  const float* value = (const float*)d_in[2];
  const float* Wq = (const float*)d_in[3];
  const float* bq = (const float*)d_in[4];
  const float* Wk = (const float*)d_in[5];
  const float* bk = (const float*)d_in[6];
  const float* Wv = (const float*)d_in[7];
  const float* bv = (const float*)d_in[8];
  const void*  pmask = d_in[9];
  float* out = (float*)d_out;
  char* ws = (char*)d_ws;

  (void)hipFuncSetAttribute((const void*)proj256_kernel,
                            hipFuncAttributeMaxDynamicSharedMemorySize, 131072);
  (void)hipFuncSetAttribute((const void*)qk256_kernel,
                            hipFuncAttributeMaxDynamicSharedMemorySize, 131072);

  // workspace layout (bytes):
  //   [0,16)            lengths (int[4])
  //   [256, +50331648)  q,k bf16 [8192][1024] + vT bf16 [4][1024][2048]
  //   [50331904, +33554432)  P bf16 [4][2048][2048]  (also v-normal temp pre-softmax)
  //   [83886336, +67108864)  union: {X bf16 + W bf16} then scores fp32
  int* lengths = (int*)ws;
  u16* q   = (u16*)(ws + 256);
  u16* kk  = q  + (size_t)MFLAT * D_;
  u16* vT  = kk + (size_t)MFLAT * D_;
  u16* Pbuf = (u16*)(ws + 50331904ull);
  u16* vbuf = Pbuf;
  char* scratch = ws + 83886336ull;
  u16* Xb = (u16*)scratch;
  u16* Wb = Xb + 3ull * MFLAT * E_;
  float* scores = (float*)scratch;

  // P0: converts (2 launches) + lengths
  cvt3_kernel<<<dim3(2048), 256, 0, stream>>>(query, key_, value, Xb, (MFLAT*E_)/4);
  cvt3_kernel<<<dim3(512),  256, 0, stream>>>(Wq, Wk, Wv, Wb, (D_*E_)/4);
  lengths_kernel<<<dim3(1), 256, 0, stream>>>(pmask, lengths);

  // P1: projections (z = 0:q, 1:k, 2:v-normal into Pbuf region)
  proj256_kernel<<<dim3(384), 512, 131072, stream>>>(Xb, Wb, bq, bk, bv, q, kk, vbuf);

  // P1b: v -> vT
  transpose_kernel<<<dim3(16, 32, 4), 256, 0, stream>>>(vbuf, vT);

  // P2: QK^T (144 valid triangle tiles), scores fp32 (overwrites Xb/Wb)
  qk256_kernel<<<dim3(144), 512, 131072, stream>>>(q, kk, lengths, scores);

  // P3: softmax -> bf16 P (overwrites vbuf)
  softmax_kernel<<<dim3(2048, 4), 256, 0, stream>>>(scores, lengths, Pbuf);

  // P4: PV -> out
  pv_kernel<<<dim3(8, 16, 4), 256, 0, stream>>>(Pbuf, vT, lengths, out);
}

// Round 7
// 344.951 us; speedup vs baseline: 1.0993x; 1.0293x over previous
//
#include <hip/hip_runtime.h>
#include <cstdint>
#include <cstddef>

#define B_ 4
#define S_ 2048
#define E_ 1024
#define D_ 1024
#define MFLAT (B_*S_)

typedef __attribute__((ext_vector_type(4))) float f32x4;
typedef __attribute__((ext_vector_type(8))) short short8;
typedef unsigned short u16;
typedef unsigned int   u32;

__device__ __forceinline__ u16 f2bf(float f) {
  u32 u = __float_as_uint(f);
  u = (u + 0x7fffu + ((u >> 16) & 1u)) >> 16;   // RNE
  return (u16)u;
}

__device__ __forceinline__ void gll16(const void* g, void* lds) {
  __builtin_amdgcn_global_load_lds(
      (const __attribute__((address_space(1))) void*)g,
      (__attribute__((address_space(3))) void*)lds, 16, 0, 0);
}

#define BARRIER() do { asm volatile("" ::: "memory"); \
                       __builtin_amdgcn_s_barrier();  \
                       asm volatile("" ::: "memory"); } while (0)

// =====================================================================
// 256x256 NT GEMM core: staggered-consumption 4-phase schedule.
//   C[m][n] = sum_k A[m][k]*B[n][k]; A/B bf16 row-major K-contiguous.
//   BK=64, dbuf 128 KiB LDS. 1 barrier/phase. Phase p computes mf {2p,2p+1}
//   (A-quarter p); B-frags read once at p0, held in regs.
//   Staging: 8KB units (1 gll16/thread), 2/phase: p0:[Bu0,Bu1] p1:[Bu2,Bu3]
//   p2:[Aq0,Aq1] p3:[Aq2,Aq3], targeting tile t+1's buffer.
//   Counted per-phase vmcnt {3,4,5,6}: drained units have 2-4 phase lead.
//   Ledger (steady, 2 issues/phase, 8 in flight at p0):
//     p0: 8 -> vmcnt(3) drains Bu0-3(t),Aq0(t); p1: 5 -> (4) drains Aq1;
//     p2: 6 -> (5) drains Aq2; p3: 7 -> (6) drains Aq3. Valid for any NT>=1
//     (tail stages wrap to tile 0: harmless prefetch, uniform counts).
//   LDS map: A buf0 [0,32K) buf1 [32K,64K); B buf0 [64K,96K) buf1 [96K,128K).
//   Swizzle (validated R2/R4, conflicts=0): col_byte ^= ((row&7)<<4);
//   inverse-swizzled global source + swizzled ds_read.
// =====================================================================
__device__ __forceinline__ void gemm256s_core(
    const u16* __restrict__ Ag, int lda,
    const u16* __restrict__ Bg, int ldb,
    int NT, char* lds, f32x4 acc[8][4])
{
  const int tid = threadIdx.x;          // 0..511
  const int l = tid & 63;
  const int w = tid >> 6;
  const int wm = w >> 2, wn = w & 3;

  // staging invariants (unit = 8KB, 1 gll16/thread; dest lane-linear per wave)
  const int scs = (((tid & 7) ^ ((tid >> 3) & 7)) << 4);  // pre-swizzled src col
  const char* srcA = (const char*)Ag
      + (size_t)((tid >> 8) * 128 + ((tid & 255) >> 3)) * (size_t)lda * 2 + scs;
  const char* srcB = (const char*)Bg + (size_t)(tid >> 3) * (size_t)ldb * 2 + scs;
  const size_t astep = (size_t)lda * 64;    // 32 rows (bytes)
  const size_t bstep = (size_t)ldb * 128;   // 64 rows (bytes)
  char* dA0 = lds + ((tid >> 8) << 14) + ((tid & 255) << 4);
  char* dB0 = lds + 65536 + (tid << 4);

  // fragment-read invariants
  const int fr = l & 15, kq = l >> 4;
  const int kx = (l & 7) << 4;
  const int kc0 = (kq << 4) ^ kx;
  const int kc1 = ((kq << 4) + 64) ^ kx;
  const int aoff = (wm << 14) + fr * 128;
  const int boff = 65536 + wn * 8192 + fr * 128;

#define SG_A(q) gll16(srcA + (q)*astep + tso, dA0 + sb + (q)*4096)
#define SG_B(u) gll16(srcB + (u)*bstep + tso, dB0 + sb + (u)*8192)
#define LDA_(mf, kc) (*(const short8*)(lds + bufo + aoff + (mf)*2048 + (kc)))
#define LDB_(nf, kc) (*(const short8*)(lds + bufo + boff + (nf)*2048 + (kc)))
#define WAIT_LGKM() asm volatile("s_waitcnt lgkmcnt(0)" ::: "memory")
#define MFMA_PH(p) do {                                                          \
    __builtin_amdgcn_s_setprio(1);                                               \
    _Pragma("unroll")                                                            \
    for (int i_ = 0; i_ < 2; ++i_) {                                             \
      _Pragma("unroll")                                                          \
      for (int j_ = 0; j_ < 4; ++j_) {                                           \
        acc[2*(p)+i_][j_] = __builtin_amdgcn_mfma_f32_16x16x32_bf16(             \
            areg[i_][0], breg[j_][0], acc[2*(p)+i_][j_], 0, 0, 0);               \
        acc[2*(p)+i_][j_] = __builtin_amdgcn_mfma_f32_16x16x32_bf16(             \
            areg[i_][1], breg[j_][1], acc[2*(p)+i_][j_], 0, 0, 0);               \
      }                                                                          \
    }                                                                            \
    __builtin_amdgcn_s_setprio(0);                                               \
  } while (0)

  short8 areg[2][2], breg[4][2];

  // prologue: stage all 8 units of tile 0 (queue order = steady order)
  {
    const size_t tso = 0; const int sb = 0;
    SG_B(0); SG_B(1); SG_B(2); SG_B(3);
    SG_A(0); SG_A(1); SG_A(2); SG_A(3);
  }

  for (int t = 0; t < NT; ++t) {
    const int bufo = (t & 1) << 15;
    const int sb = ((t + 1) & 1) << 15;
    const int tsi = (t + 1 == NT) ? 0 : (t + 1);   // wrapped tail source
    const size_t tso = (size_t)tsi << 7;           // *128 bytes (64 k * 2B)

    // phase 0: B-all + Aq0 resident; read B-frags + A mf0-1; stage Bu0,Bu1(t+1)
    asm volatile("s_waitcnt vmcnt(3)" ::: "memory");
    BARRIER();
#pragma unroll
    for (int nf = 0; nf < 4; ++nf) { breg[nf][0] = LDB_(nf, kc0); breg[nf][1] = LDB_(nf, kc1); }
#pragma unroll
    for (int i = 0; i < 2; ++i) { areg[i][0] = LDA_(i, kc0); areg[i][1] = LDA_(i, kc1); }
    SG_B(0); SG_B(1);
    WAIT_LGKM();
    MFMA_PH(0);

    // phase 1: Aq1 resident; read A mf2-3; stage Bu2,Bu3(t+1)
    asm volatile("s_waitcnt vmcnt(4)" ::: "memory");
    BARRIER();
#pragma unroll
    for (int i = 0; i < 2; ++i) { areg[i][0] = LDA_(2+i, kc0); areg[i][1] = LDA_(2+i, kc1); }
    SG_B(2); SG_B(3);
    WAIT_LGKM();
    MFMA_PH(1);

    // phase 2: Aq2 resident; read A mf4-5; stage Aq0,Aq1(t+1)
    asm volatile("s_waitcnt vmcnt(5)" ::: "memory");
    BARRIER();
#pragma unroll
    for (int i = 0; i < 2; ++i) { areg[i][0] = LDA_(4+i, kc0); areg[i][1] = LDA_(4+i, kc1); }
    SG_A(0); SG_A(1);
    WAIT_LGKM();
    MFMA_PH(2);

    // phase 3: Aq3 resident; read A mf6-7; stage Aq2,Aq3(t+1)
    asm volatile("s_waitcnt vmcnt(6)" ::: "memory");
    BARRIER();
#pragma unroll
    for (int i = 0; i < 2; ++i) { areg[i][0] = LDA_(6+i, kc0); areg[i][1] = LDA_(6+i, kc1); }
    SG_A(2); SG_A(3);
    WAIT_LGKM();
    MFMA_PH(3);
  }
  // drain in-flight LDS DMA before LDS hand-off / block end
  asm volatile("s_waitcnt vmcnt(0)" ::: "memory");
  BARRIER();
#undef SG_A
#undef SG_B
#undef LDA_
#undef LDB_
#undef WAIT_LGKM
#undef MFMA_PH
}

// ---------- fp32 -> bf16 convert, 3 equal segments ----------
__global__ __launch_bounds__(256) void cvt3_kernel(
    const float* __restrict__ s0, const float* __restrict__ s1,
    const float* __restrict__ s2, u16* __restrict__ dst, int segn4)
{
  int idx = blockIdx.x * blockDim.x + threadIdx.x;
  int stride = gridDim.x * blockDim.x;
  const int total = 3 * segn4;
  for (int i = idx; i < total; i += stride) {
    int s = i / segn4;
    int off = i - s * segn4;
    const float4* sp = (s == 0) ? (const float4*)s0 : (s == 1) ? (const float4*)s1 : (const float4*)s2;
    float4 f = sp[off];
    ushort4 o;
    o.x = f2bf(f.x); o.y = f2bf(f.y); o.z = f2bf(f.z); o.w = f2bf(f.w);
    ((ushort4*)dst)[i] = o;
  }
}

// ---------- per-batch valid lengths from padding_mask ----------
__global__ __launch_bounds__(256) void lengths_kernel(const void* __restrict__ mask,
                                                      int* __restrict__ lengths) {
  __shared__ int isbytes;
  const int t = threadIdx.x;
  if (t == 0) isbytes = 0;
  __syncthreads();
  const int* wi = (const int*)mask;
  int bad = 0;
  for (int idx = t; idx < (B_*S_)/4; idx += 256) {
    int v = wi[idx];
    if (v != 0 && v != 1) bad = 1;
  }
  if (bad) atomicOr(&isbytes, 1);
  __syncthreads();
  const int isb = isbytes;
  const int w = t >> 6, l = t & 63;
  const unsigned char* mb = (const unsigned char*)mask;
  int cnt = 0;
  for (int j = l; j < S_; j += 64) {
    int val = isb ? (int)mb[(size_t)w*S_ + j] : wi[(size_t)w*S_ + j];
    cnt += (val == 0);
  }
#pragma unroll
  for (int off = 32; off >= 1; off >>= 1) cnt += __shfl_xor(cnt, off);
  if (l == 0) lengths[w] = cnt;
}

// ---------- QKV projection: C = X @ W^T + b, bf16 out. 384 = 8*48 XCD swz ----------
__global__ __launch_bounds__(512, 2) void proj256_kernel(
    const u16* __restrict__ X, const u16* __restrict__ W,
    const float* __restrict__ bq, const float* __restrict__ bk, const float* __restrict__ bv,
    u16* __restrict__ q, u16* __restrict__ k, u16* __restrict__ v)
{
  extern __shared__ char lds[];
  const int bid = blockIdx.x;
  const int wg = (bid & 7) * 48 + (bid >> 3);
  const int z  = wg >> 7;
  const int rem = wg & 127;
  const int nt = rem >> 5;
  const int mt = rem & 31;      // consecutive blocks share W panel

  const u16* Xz = X + (size_t)z * ((size_t)MFLAT * E_) + (size_t)(mt*256)*E_;
  const u16* Wz = W + (size_t)z * ((size_t)D_ * E_)    + (size_t)(nt*256)*E_;
  f32x4 acc[8][4];
#pragma unroll
  for (int i = 0; i < 8; ++i)
#pragma unroll
    for (int j = 0; j < 4; ++j) acc[i][j] = (f32x4){0.f,0.f,0.f,0.f};

  gemm256s_core(Xz, E_, Wz, E_, E_/64, lds, acc);

  const float* bias = (z == 0) ? bq : (z == 1) ? bk : bv;
  u16* out = (z == 0) ? q : (z == 1) ? k : v;
  const int tid = threadIdx.x, w = tid >> 6, l = tid & 63;
  const int wm = w >> 2, wn = w & 3;
  const int fr = l & 15, kq = l >> 4;
  const int orow0 = mt*256 + wm*128 + kq*4;
  const int ocol0 = nt*256 + wn*64 + fr;
#pragma unroll
  for (int nf = 0; nf < 4; ++nf) {
    const int col = ocol0 + nf*16;
    const float bcol = bias[col];
#pragma unroll
    for (int mf = 0; mf < 8; ++mf)
#pragma unroll
      for (int r = 0; r < 4; ++r)
        out[(size_t)(orow0 + mf*16 + r)*D_ + col] = f2bf(acc[mf][nf][r] + bcol);
  }
}

// ---------- v [b][s][d] -> vT [b][d][s] ----------
__global__ __launch_bounds__(256) void transpose_kernel(
    const u16* __restrict__ v, u16* __restrict__ vT)
{
  __shared__ u16 tl[64][68];
  const int xt = blockIdx.x;
  const int yt = blockIdx.y;
  const int b  = blockIdx.z;
  const int t = threadIdx.x;
  const int r0 = t >> 4;
  const int c4 = (t & 15) << 2;
  const u16* src = v + ((size_t)b*S_ + yt*64)*D_ + xt*64;
#pragma unroll
  for (int rr = r0; rr < 64; rr += 16) {
    ushort4 u = *(const ushort4*)(src + (size_t)rr*D_ + c4);
    tl[rr][c4+0] = u.x; tl[rr][c4+1] = u.y; tl[rr][c4+2] = u.z; tl[rr][c4+3] = u.w;
  }
  __syncthreads();
  u16* dst = vT + ((size_t)b*D_ + xt*64)*S_ + yt*64;
#pragma unroll
  for (int rr = r0; rr < 64; rr += 16) {
    ushort4 u;
    u.x = tl[c4+0][rr]; u.y = tl[c4+1][rr]; u.z = tl[c4+2][rr]; u.w = tl[c4+3][rr];
    *(ushort4*)(dst + (size_t)rr*S_ + c4) = u;
  }
}

// ---------- QK^T, valid lower-triangle 256-tiles only. 144 = 8*18 XCD swz ----------
__global__ __launch_bounds__(512, 2) void qk256_kernel(
    const u16* __restrict__ q, const u16* __restrict__ k,
    const int* __restrict__ lengths, float* __restrict__ scores)
{
  const int bid = blockIdx.x;
  const int wg = (bid & 7) * 18 + (bid >> 3);
  const int b = wg / 36;
  const int r = wg - b * 36;
  int ty = (int)((sqrtf(8.0f * (float)r + 1.0f) - 1.0f) * 0.5f);
  while ((ty + 1) * (ty + 2) / 2 <= r) ++ty;
  while (ty * (ty + 1) / 2 > r) --ty;
  const int tx = r - ty * (ty + 1) / 2;

  const int len = lengths[b];
  if (tx * 256 >= len) return;
  extern __shared__ char lds[];
  f32x4 acc[8][4];
#pragma unroll
  for (int i = 0; i < 8; ++i)
#pragma unroll
    for (int j = 0; j < 4; ++j) acc[i][j] = (f32x4){0.f,0.f,0.f,0.f};
  const u16* Aq = q + ((size_t)b*S_ + (size_t)ty*256) * D_;
  const u16* Bk = k + ((size_t)b*S_ + (size_t)tx*256) * D_;
  gemm256s_core(Aq, D_, Bk, D_, D_/64, lds, acc);

  const int tid = threadIdx.x, w = tid >> 6, l = tid & 63;
  const int wm = w >> 2, wn = w & 3;
  const int fr = l & 15, kq = l >> 4;
  const int orow0 = ty*256 + wm*128 + kq*4;
  const int ocol0 = tx*256 + wn*64 + fr;
  float* sb = scores + (size_t)b*S_*S_;
#pragma unroll
  for (int mf = 0; mf < 8; ++mf)
#pragma unroll
    for (int nf = 0; nf < 4; ++nf)
#pragma unroll
      for (int r2 = 0; r2 < 4; ++r2)
        sb[(size_t)(orow0 + mf*16 + r2)*S_ + (ocol0 + nf*16)] = acc[mf][nf][r2] * 0.03125f;
}

// ---------- row softmax (exact fp32), bf16 P with zero fill ----------
__global__ __launch_bounds__(256) void softmax_kernel(
    const float* __restrict__ scores, const int* __restrict__ lengths,
    u16* __restrict__ P)
{
  const int i = blockIdx.x, b = blockIdx.y;
  const int len = lengths[b];
  const int kmax = min(i + 1, len);
  const float* row = scores + ((size_t)b*S_ + i)*S_;
  u16* prow = P + ((size_t)b*S_ + i)*S_;
  const int t = threadIdx.x;
  const int j0 = t * 8;
  float v[8];
  {
    float4 x0 = *(const float4*)(row + j0);
    float4 x1 = *(const float4*)(row + j0 + 4);
    v[0]=x0.x; v[1]=x0.y; v[2]=x0.z; v[3]=x0.w;
    v[4]=x1.x; v[5]=x1.y; v[6]=x1.z; v[7]=x1.w;
  }
  float m = -3.4e38f;
#pragma unroll
  for (int e = 0; e < 8; ++e) if (j0 + e < kmax) m = fmaxf(m, v[e]);
#pragma unroll
  for (int off = 32; off >= 1; off >>= 1) m = fmaxf(m, __shfl_xor(m, off));
  __shared__ float redm[4], reds[4];
  if ((t & 63) == 0) redm[t >> 6] = m;
  __syncthreads();
  m = fmaxf(fmaxf(redm[0], redm[1]), fmaxf(redm[2], redm[3]));
  float s = 0.f, ex[8];
#pragma unroll
  for (int e = 0; e < 8; ++e) {
    ex[e] = (j0 + e < kmax) ? __expf(v[e] - m) : 0.f;
    s += ex[e];
  }
#pragma unroll
  for (int off = 32; off >= 1; off >>= 1) s += __shfl_xor(s, off);
  if ((t & 63) == 0) reds[t >> 6] = s;
  __syncthreads();
  s = reds[0] + reds[1] + reds[2] + reds[3];
  const float inv = 1.0f / s;
  short8 o;
#pragma unroll
  for (int e = 0; e < 8; ++e) o[e] = (short)f2bf(ex[e] * inv);
  *(short8*)(prow + j0) = o;
}

// ---------- PV GEMM, 256^2 core, causal K-cap. 128 = 8*16 XCD swz ----------
__global__ __launch_bounds__(512, 2) void pv256_kernel(
    const u16* __restrict__ P, const u16* __restrict__ vT,
    const int* __restrict__ lengths, float* __restrict__ out)
{
  extern __shared__ char lds[];
  const int bid = blockIdx.x;
  const int wg = (bid & 7) * 16 + (bid >> 3);
  const int b = wg >> 5;
  const int rem = wg & 31;
  const int ty = rem >> 2;      // 8 q-row tiles
  const int xt = rem & 3;       // 4 d-col tiles
  const int len = lengths[b];
  const int kend = min(ty * 256 + 256, len);
  const int NT = (kend + 63) >> 6;     // >= 1 since len >= 1

  f32x4 acc[8][4];
#pragma unroll
  for (int i = 0; i < 8; ++i)
#pragma unroll
    for (int j = 0; j < 4; ++j) acc[i][j] = (f32x4){0.f,0.f,0.f,0.f};
  const u16* Ap = P  + ((size_t)b*S_ + (size_t)ty*256) * S_;
  const u16* Bv = vT + ((size_t)b*D_ + (size_t)xt*256) * S_;
  gemm256s_core(Ap, S_, Bv, S_, NT, lds, acc);

  const int tid = threadIdx.x, w = tid >> 6, l = tid & 63;
  const int wm = w >> 2, wn = w & 3;
  const int fr = l & 15, kq = l >> 4;
  const int orow0 = ty*256 + wm*128 + kq*4;
  const int ocol0 = xt*256 + wn*64 + fr;
  float* ob = out + (size_t)b*S_*D_;
#pragma unroll
  for (int mf = 0; mf < 8; ++mf)
#pragma unroll
    for (int nf = 0; nf < 4; ++nf)
#pragma unroll
      for (int r2 = 0; r2 < 4; ++r2)
        ob[(size_t)(orow0 + mf*16 + r2)*D_ + (ocol0 + nf*16)] = acc[mf][nf][r2];
}

// ---------- launch ----------
extern "C" void kernel_launch(void* const* d_in, const int* in_sizes, int n_in,
                              void* d_out, int out_size, void* d_ws, size_t ws_size,
                              hipStream_t stream)
{
  const float* query = (const float*)d_in[0];
  const float* key_  = (const float*)d_in[1];
  const float* value = (const float*)d_in[2];
  const float* Wq = (const float*)d_in[3];
  const float* bq = (const float*)d_in[4];
  const float* Wk = (const float*)d_in[5];
  const float* bk = (const float*)d_in[6];
  const float* Wv = (const float*)d_in[7];
  const float* bv = (const float*)d_in[8];
  const void*  pmask = d_in[9];
  float* out = (float*)d_out;
  char* ws = (char*)d_ws;

  (void)hipFuncSetAttribute((const void*)proj256_kernel,
                            hipFuncAttributeMaxDynamicSharedMemorySize, 131072);
  (void)hipFuncSetAttribute((const void*)qk256_kernel,
                            hipFuncAttributeMaxDynamicSharedMemorySize, 131072);
  (void)hipFuncSetAttribute((const void*)pv256_kernel,
                            hipFuncAttributeMaxDynamicSharedMemorySize, 131072);

  // workspace layout (bytes):
  //   [0,16)                 lengths (int[4])
  //   [256, +50331648)       q,k bf16 [8192][1024] + vT bf16 [4][1024][2048]
  //   [50331904, +33554432)  P bf16 [4][2048][2048] (also v-normal pre-softmax)
  //   [83886336, +67108864)  union: {X bf16 + W bf16} then scores fp32
  int* lengths = (int*)ws;
  u16* q   = (u16*)(ws + 256);
  u16* kk  = q  + (size_t)MFLAT * D_;
  u16* vT  = kk + (size_t)MFLAT * D_;
  u16* Pbuf = (u16*)(ws + 50331904ull);
  u16* vbuf = Pbuf;
  char* scratch = ws + 83886336ull;
  u16* Xb = (u16*)scratch;
  u16* Wb = Xb + 3ull * MFLAT * E_;
  float* scores = (float*)scratch;

  cvt3_kernel<<<dim3(2048), 256, 0, stream>>>(query, key_, value, Xb, (MFLAT*E_)/4);
  cvt3_kernel<<<dim3(512),  256, 0, stream>>>(Wq, Wk, Wv, Wb, (D_*E_)/4);
  lengths_kernel<<<dim3(1), 256, 0, stream>>>(pmask, lengths);

  proj256_kernel<<<dim3(384), 512, 131072, stream>>>(Xb, Wb, bq, bk, bv, q, kk, vbuf);

  transpose_kernel<<<dim3(16, 32, 4), 256, 0, stream>>>(vbuf, vT);

  qk256_kernel<<<dim3(144), 512, 131072, stream>>>(q, kk, lengths, scores);

  softmax_kernel<<<dim3(2048, 4), 256, 0, stream>>>(scores, lengths, Pbuf);

  pv256_kernel<<<dim3(128), 512, 131072, stream>>>(Pbuf, vT, lengths, out);
}

// Round 8
// 332.248 us; speedup vs baseline: 1.1413x; 1.0382x over previous
//
#include <hip/hip_runtime.h>
#include <cstdint>
#include <cstddef>

#define B_ 4
#define S_ 2048
#define E_ 1024
#define D_ 1024
#define MFLAT (B_*S_)

typedef __attribute__((ext_vector_type(4))) float f32x4;
typedef __attribute__((ext_vector_type(8))) short short8;
typedef unsigned short u16;
typedef unsigned int   u32;

__device__ __forceinline__ u16 f2bf(float f) {
  u32 u = __float_as_uint(f);
  u = (u + 0x7fffu + ((u >> 16) & 1u)) >> 16;   // RNE
  return (u16)u;
}

__device__ __forceinline__ void gll16(const void* g, void* lds) {
  __builtin_amdgcn_global_load_lds(
      (const __attribute__((address_space(1))) void*)g,
      (__attribute__((address_space(3))) void*)lds, 16, 0, 0);
}

#define BARRIER() do { asm volatile("" ::: "memory"); \
                       __builtin_amdgcn_s_barrier();  \
                       asm volatile("" ::: "memory"); } while (0)

// =====================================================================
// 256x256 NT GEMM core (R5/R7, kept for proj as control): staggered
// 4-phase, counted vmcnt {3,4,5,6}. See R5 ledger. 669 TF measured.
// =====================================================================
__device__ __forceinline__ void gemm256s_core(
    const u16* __restrict__ Ag, int lda,
    const u16* __restrict__ Bg, int ldb,
    int NT, char* lds, f32x4 acc[8][4])
{
  const int tid = threadIdx.x;          // 0..511
  const int l = tid & 63;
  const int w = tid >> 6;
  const int wm = w >> 2, wn = w & 3;

  const int scs = (((tid & 7) ^ ((tid >> 3) & 7)) << 4);  // pre-swizzled src col
  const char* srcA = (const char*)Ag
      + (size_t)((tid >> 8) * 128 + ((tid & 255) >> 3)) * (size_t)lda * 2 + scs;
  const char* srcB = (const char*)Bg + (size_t)(tid >> 3) * (size_t)ldb * 2 + scs;
  const size_t astep = (size_t)lda * 64;    // 32 rows (bytes)
  const size_t bstep = (size_t)ldb * 128;   // 64 rows (bytes)
  char* dA0 = lds + ((tid >> 8) << 14) + ((tid & 255) << 4);
  char* dB0 = lds + 65536 + (tid << 4);

  const int fr = l & 15, kq = l >> 4;
  const int kx = (l & 7) << 4;
  const int kc0 = (kq << 4) ^ kx;
  const int kc1 = ((kq << 4) + 64) ^ kx;
  const int aoff = (wm << 14) + fr * 128;
  const int boff = 65536 + wn * 8192 + fr * 128;

#define SG_A(q) gll16(srcA + (q)*astep + tso, dA0 + sb + (q)*4096)
#define SG_B(u) gll16(srcB + (u)*bstep + tso, dB0 + sb + (u)*8192)
#define LDA_(mf, kc) (*(const short8*)(lds + bufo + aoff + (mf)*2048 + (kc)))
#define LDB_(nf, kc) (*(const short8*)(lds + bufo + boff + (nf)*2048 + (kc)))
#define WAIT_LGKM() asm volatile("s_waitcnt lgkmcnt(0)" ::: "memory")
#define MFMA_PH(p) do {                                                          \
    __builtin_amdgcn_s_setprio(1);                                               \
    _Pragma("unroll")                                                            \
    for (int i_ = 0; i_ < 2; ++i_) {                                             \
      _Pragma("unroll")                                                          \
      for (int j_ = 0; j_ < 4; ++j_) {                                           \
        acc[2*(p)+i_][j_] = __builtin_amdgcn_mfma_f32_16x16x32_bf16(             \
            areg[i_][0], breg[j_][0], acc[2*(p)+i_][j_], 0, 0, 0);               \
        acc[2*(p)+i_][j_] = __builtin_amdgcn_mfma_f32_16x16x32_bf16(             \
            areg[i_][1], breg[j_][1], acc[2*(p)+i_][j_], 0, 0, 0);               \
      }                                                                          \
    }                                                                            \
    __builtin_amdgcn_s_setprio(0);                                               \
  } while (0)

  short8 areg[2][2], breg[4][2];

  {
    const size_t tso = 0; const int sb = 0;
    SG_B(0); SG_B(1); SG_B(2); SG_B(3);
    SG_A(0); SG_A(1); SG_A(2); SG_A(3);
  }

  for (int t = 0; t < NT; ++t) {
    const int bufo = (t & 1) << 15;
    const int sb = ((t + 1) & 1) << 15;
    const int tsi = (t + 1 == NT) ? 0 : (t + 1);
    const size_t tso = (size_t)tsi << 7;

    asm volatile("s_waitcnt vmcnt(3)" ::: "memory");
    BARRIER();
#pragma unroll
    for (int nf = 0; nf < 4; ++nf) { breg[nf][0] = LDB_(nf, kc0); breg[nf][1] = LDB_(nf, kc1); }
#pragma unroll
    for (int i = 0; i < 2; ++i) { areg[i][0] = LDA_(i, kc0); areg[i][1] = LDA_(i, kc1); }
    SG_B(0); SG_B(1);
    WAIT_LGKM();
    MFMA_PH(0);

    asm volatile("s_waitcnt vmcnt(4)" ::: "memory");
    BARRIER();
#pragma unroll
    for (int i = 0; i < 2; ++i) { areg[i][0] = LDA_(2+i, kc0); areg[i][1] = LDA_(2+i, kc1); }
    SG_B(2); SG_B(3);
    WAIT_LGKM();
    MFMA_PH(1);

    asm volatile("s_waitcnt vmcnt(5)" ::: "memory");
    BARRIER();
#pragma unroll
    for (int i = 0; i < 2; ++i) { areg[i][0] = LDA_(4+i, kc0); areg[i][1] = LDA_(4+i, kc1); }
    SG_A(0); SG_A(1);
    WAIT_LGKM();
    MFMA_PH(2);

    asm volatile("s_waitcnt vmcnt(6)" ::: "memory");
    BARRIER();
#pragma unroll
    for (int i = 0; i < 2; ++i) { areg[i][0] = LDA_(6+i, kc0); areg[i][1] = LDA_(6+i, kc1); }
    SG_A(2); SG_A(3);
    WAIT_LGKM();
    MFMA_PH(3);
  }
  asm volatile("s_waitcnt vmcnt(0)" ::: "memory");
  BARRIER();
#undef SG_A
#undef SG_B
#undef LDA_
#undef LDB_
#undef WAIT_LGKM
#undef MFMA_PH
}

// =====================================================================
// NEW (R8): 128x128 NT GEMM core, BK=64, dbuf 64 KiB LDS -> 2 blocks/CU.
//   256 thr = 4 waves (2x2), per-wave 64x64 = 4x4 frags, 32 MFMA/tile.
//   Staging: 8 gll16/thread/tile (A rows (tid>>3)+32s, B same; lane-linear
//   dest verified: dest = wavebase + lane*16). Swizzle col_byte ^=
//   ((row&7)<<4) (2-way only, free) via inverse-swizzled source + XOR read.
//   Loop: SG8(t+1) -> vmcnt(8) [drains tile t, leaves t+1 in flight] ->
//   barrier -> 16x ds_read_b128 -> setprio+32 MFMA -> barrier (reads done
//   before next SG8 overwrites this buffer).
//   LDS map: A buf0 [0,16K) buf1 [16K,32K); B buf0 [32K,48K) buf1 [48K,64K).
// =====================================================================
__device__ __forceinline__ void gemm128_core(
    const u16* __restrict__ Ag, int lda,
    const u16* __restrict__ Bg, int ldb,
    int NT, char* lds, f32x4 acc[4][4])
{
  const int tid = threadIdx.x;          // 0..255
  const int l = tid & 63;
  const int w = tid >> 6;
  const int wm = w >> 1, wn = w & 1;

  const int scs = (((tid & 7) ^ ((tid >> 3) & 7)) << 4);
  const char* srcA = (const char*)Ag + (size_t)(tid >> 3) * (size_t)lda * 2 + scs;
  const char* srcB = (const char*)Bg + (size_t)(tid >> 3) * (size_t)ldb * 2 + scs;
  const size_t asw = (size_t)lda * 64;   // 32 rows in bytes
  const size_t bsw = (size_t)ldb * 64;
  char* dA0 = lds + (tid << 4);
  char* dB0 = lds + 32768 + (tid << 4);

  const int fr = l & 15, kq = l >> 4;
  const int kx = (l & 7) << 4;
  const int kc0 = (kq << 4) ^ kx;
  const int kc1 = ((kq << 4) + 64) ^ kx;
  const int aoff = wm * 8192 + fr * 128;
  const int boff = 32768 + wn * 8192 + fr * 128;

#define SG8(tk) do {                                                             \
    const size_t ko = (size_t)(tk) << 7;                                         \
    char* da = dA0 + sbuf; char* db = dB0 + sbuf;                                \
    gll16(srcA + ko,           da);                                              \
    gll16(srcA + ko +   asw,   da + 4096);                                       \
    gll16(srcA + ko + 2*asw,   da + 8192);                                       \
    gll16(srcA + ko + 3*asw,   da + 12288);                                      \
    gll16(srcB + ko,           db);                                              \
    gll16(srcB + ko +   bsw,   db + 4096);                                       \
    gll16(srcB + ko + 2*bsw,   db + 8192);                                       \
    gll16(srcB + ko + 3*bsw,   db + 12288);                                      \
  } while (0)

  short8 a8[4][2], b8[4][2];
  { const int sbuf = 0; SG8(0); }

  for (int t = 0; t < NT; ++t) {
    const int bufo = (t & 1) << 14;
    const int sbuf = ((t + 1) & 1) << 14;
    if (t + 1 < NT) {
      SG8(t + 1);
      asm volatile("s_waitcnt vmcnt(8)" ::: "memory");   // tile t resident
    } else {
      asm volatile("s_waitcnt vmcnt(0)" ::: "memory");
    }
    BARRIER();
#pragma unroll
    for (int mf = 0; mf < 4; ++mf) {
      a8[mf][0] = *(const short8*)(lds + bufo + aoff + mf*2048 + kc0);
      a8[mf][1] = *(const short8*)(lds + bufo + aoff + mf*2048 + kc1);
    }
#pragma unroll
    for (int nf = 0; nf < 4; ++nf) {
      b8[nf][0] = *(const short8*)(lds + bufo + boff + nf*2048 + kc0);
      b8[nf][1] = *(const short8*)(lds + bufo + boff + nf*2048 + kc1);
    }
    __builtin_amdgcn_s_setprio(1);
#pragma unroll
    for (int mf = 0; mf < 4; ++mf)
#pragma unroll
      for (int nf = 0; nf < 4; ++nf) {
        acc[mf][nf] = __builtin_amdgcn_mfma_f32_16x16x32_bf16(a8[mf][0], b8[nf][0], acc[mf][nf], 0, 0, 0);
        acc[mf][nf] = __builtin_amdgcn_mfma_f32_16x16x32_bf16(a8[mf][1], b8[nf][1], acc[mf][nf], 0, 0, 0);
      }
    __builtin_amdgcn_s_setprio(0);
    BARRIER();                           // reads done before next SG8 overwrite
  }
#undef SG8
}

// ---------- fp32 -> bf16 convert, 3 equal segments ----------
__global__ __launch_bounds__(256) void cvt3_kernel(
    const float* __restrict__ s0, const float* __restrict__ s1,
    const float* __restrict__ s2, u16* __restrict__ dst, int segn4)
{
  int idx = blockIdx.x * blockDim.x + threadIdx.x;
  int stride = gridDim.x * blockDim.x;
  const int total = 3 * segn4;
  for (int i = idx; i < total; i += stride) {
    int s = i / segn4;
    int off = i - s * segn4;
    const float4* sp = (s == 0) ? (const float4*)s0 : (s == 1) ? (const float4*)s1 : (const float4*)s2;
    float4 f = sp[off];
    ushort4 o;
    o.x = f2bf(f.x); o.y = f2bf(f.y); o.z = f2bf(f.z); o.w = f2bf(f.w);
    ((ushort4*)dst)[i] = o;
  }
}

// ---------- per-batch valid lengths from padding_mask ----------
__global__ __launch_bounds__(256) void lengths_kernel(const void* __restrict__ mask,
                                                      int* __restrict__ lengths) {
  __shared__ int isbytes;
  const int t = threadIdx.x;
  if (t == 0) isbytes = 0;
  __syncthreads();
  const int* wi = (const int*)mask;
  int bad = 0;
  for (int idx = t; idx < (B_*S_)/4; idx += 256) {
    int v = wi[idx];
    if (v != 0 && v != 1) bad = 1;
  }
  if (bad) atomicOr(&isbytes, 1);
  __syncthreads();
  const int isb = isbytes;
  const int w = t >> 6, l = t & 63;
  const unsigned char* mb = (const unsigned char*)mask;
  int cnt = 0;
  for (int j = l; j < S_; j += 64) {
    int val = isb ? (int)mb[(size_t)w*S_ + j] : wi[(size_t)w*S_ + j];
    cnt += (val == 0);
  }
#pragma unroll
  for (int off = 32; off >= 1; off >>= 1) cnt += __shfl_xor(cnt, off);
  if (l == 0) lengths[w] = cnt;
}

// ---------- QKV projection: 256^2 core (R7 control). 384 = 8*48 XCD swz ----------
__global__ __launch_bounds__(512, 2) void proj256_kernel(
    const u16* __restrict__ X, const u16* __restrict__ W,
    const float* __restrict__ bq, const float* __restrict__ bk, const float* __restrict__ bv,
    u16* __restrict__ q, u16* __restrict__ k, u16* __restrict__ v)
{
  extern __shared__ char lds[];
  const int bid = blockIdx.x;
  const int wg = (bid & 7) * 48 + (bid >> 3);
  const int z  = wg >> 7;
  const int rem = wg & 127;
  const int nt = rem >> 5;
  const int mt = rem & 31;

  const u16* Xz = X + (size_t)z * ((size_t)MFLAT * E_) + (size_t)(mt*256)*E_;
  const u16* Wz = W + (size_t)z * ((size_t)D_ * E_)    + (size_t)(nt*256)*E_;
  f32x4 acc[8][4];
#pragma unroll
  for (int i = 0; i < 8; ++i)
#pragma unroll
    for (int j = 0; j < 4; ++j) acc[i][j] = (f32x4){0.f,0.f,0.f,0.f};

  gemm256s_core(Xz, E_, Wz, E_, E_/64, lds, acc);

  const float* bias = (z == 0) ? bq : (z == 1) ? bk : bv;
  u16* out = (z == 0) ? q : (z == 1) ? k : v;
  const int tid = threadIdx.x, w = tid >> 6, l = tid & 63;
  const int wm = w >> 2, wn = w & 3;
  const int fr = l & 15, kq = l >> 4;
  const int orow0 = mt*256 + wm*128 + kq*4;
  const int ocol0 = nt*256 + wn*64 + fr;
#pragma unroll
  for (int nf = 0; nf < 4; ++nf) {
    const int col = ocol0 + nf*16;
    const float bcol = bias[col];
#pragma unroll
    for (int mf = 0; mf < 8; ++mf)
#pragma unroll
      for (int r = 0; r < 4; ++r)
        out[(size_t)(orow0 + mf*16 + r)*D_ + col] = f2bf(acc[mf][nf][r] + bcol);
  }
}

// ---------- v [b][s][d] -> vT [b][d][s] ----------
__global__ __launch_bounds__(256) void transpose_kernel(
    const u16* __restrict__ v, u16* __restrict__ vT)
{
  __shared__ u16 tl[64][68];
  const int xt = blockIdx.x;
  const int yt = blockIdx.y;
  const int b  = blockIdx.z;
  const int t = threadIdx.x;
  const int r0 = t >> 4;
  const int c4 = (t & 15) << 2;
  const u16* src = v + ((size_t)b*S_ + yt*64)*D_ + xt*64;
#pragma unroll
  for (int rr = r0; rr < 64; rr += 16) {
    ushort4 u = *(const ushort4*)(src + (size_t)rr*D_ + c4);
    tl[rr][c4+0] = u.x; tl[rr][c4+1] = u.y; tl[rr][c4+2] = u.z; tl[rr][c4+3] = u.w;
  }
  __syncthreads();
  u16* dst = vT + ((size_t)b*D_ + xt*64)*S_ + yt*64;
#pragma unroll
  for (int rr = r0; rr < 64; rr += 16) {
    ushort4 u;
    u.x = tl[c4+0][rr]; u.y = tl[c4+1][rr]; u.z = tl[c4+2][rr]; u.w = tl[c4+3][rr];
    *(ushort4*)(dst + (size_t)rr*S_ + c4) = u;
  }
}

// ---------- QK^T, 128^2 core, lower-triangle 128-tiles. 544 = 8*68 XCD ----------
__global__ __launch_bounds__(256, 2) void qk128_kernel(
    const u16* __restrict__ q, const u16* __restrict__ k,
    const int* __restrict__ lengths, float* __restrict__ scores)
{
  const int bid = blockIdx.x;
  const int wg = (bid & 7) * 68 + (bid >> 3);
  const int b = wg / 136;
  const int r = wg - b * 136;
  int ty = (int)((sqrtf(8.0f * (float)r + 1.0f) - 1.0f) * 0.5f);
  while ((ty + 1) * (ty + 2) / 2 <= r) ++ty;
  while (ty * (ty + 1) / 2 > r) --ty;
  const int tx = r - ty * (ty + 1) / 2;

  const int len = lengths[b];
  if (tx * 128 >= len) return;
  extern __shared__ char lds[];
  f32x4 acc[4][4];
#pragma unroll
  for (int i = 0; i < 4; ++i)
#pragma unroll
    for (int j = 0; j < 4; ++j) acc[i][j] = (f32x4){0.f,0.f,0.f,0.f};
  const u16* Aq = q + ((size_t)b*S_ + (size_t)ty*128) * D_;
  const u16* Bk = k + ((size_t)b*S_ + (size_t)tx*128) * D_;
  gemm128_core(Aq, D_, Bk, D_, D_/64, lds, acc);

  const int tid = threadIdx.x, w = tid >> 6, l = tid & 63;
  const int wm = w >> 1, wn = w & 1;
  const int fr = l & 15, kq = l >> 4;
  const int orow0 = ty*128 + wm*64 + kq*4;
  const int ocol0 = tx*128 + wn*64 + fr;
  float* sb = scores + (size_t)b*S_*S_;
#pragma unroll
  for (int mf = 0; mf < 4; ++mf)
#pragma unroll
    for (int nf = 0; nf < 4; ++nf)
#pragma unroll
      for (int r2 = 0; r2 < 4; ++r2)
        sb[(size_t)(orow0 + mf*16 + r2)*S_ + (ocol0 + nf*16)] = acc[mf][nf][r2] * 0.03125f;
}

// ---------- row softmax (exact fp32), bf16 P, read-skip beyond kmax ----------
__global__ __launch_bounds__(256) void softmax_kernel(
    const float* __restrict__ scores, const int* __restrict__ lengths,
    u16* __restrict__ P)
{
  const int i = blockIdx.x, b = blockIdx.y;
  const int len = lengths[b];
  const int kmax = min(i + 1, len);
  const float* row = scores + ((size_t)b*S_ + i)*S_;
  u16* prow = P + ((size_t)b*S_ + i)*S_;
  const int t = threadIdx.x;
  const int j0 = t * 8;
  float v[8];
  if (j0 < kmax) {          // skip loads entirely beyond the valid prefix
    float4 x0 = *(const float4*)(row + j0);
    float4 x1 = *(const float4*)(row + j0 + 4);
    v[0]=x0.x; v[1]=x0.y; v[2]=x0.z; v[3]=x0.w;
    v[4]=x1.x; v[5]=x1.y; v[6]=x1.z; v[7]=x1.w;
  } else {
#pragma unroll
    for (int e = 0; e < 8; ++e) v[e] = 0.f;
  }
  float m = -3.4e38f;
#pragma unroll
  for (int e = 0; e < 8; ++e) if (j0 + e < kmax) m = fmaxf(m, v[e]);
#pragma unroll
  for (int off = 32; off >= 1; off >>= 1) m = fmaxf(m, __shfl_xor(m, off));
  __shared__ float redm[4], reds[4];
  if ((t & 63) == 0) redm[t >> 6] = m;
  __syncthreads();
  m = fmaxf(fmaxf(redm[0], redm[1]), fmaxf(redm[2], redm[3]));
  float s = 0.f, ex[8];
#pragma unroll
  for (int e = 0; e < 8; ++e) {
    ex[e] = (j0 + e < kmax) ? __expf(v[e] - m) : 0.f;
    s += ex[e];
  }
#pragma unroll
  for (int off = 32; off >= 1; off >>= 1) s += __shfl_xor(s, off);
  if ((t & 63) == 0) reds[t >> 6] = s;
  __syncthreads();
  s = reds[0] + reds[1] + reds[2] + reds[3];
  const float inv = 1.0f / s;
  short8 o;
#pragma unroll
  for (int e = 0; e < 8; ++e) o[e] = (short)f2bf(ex[e] * inv);
  *(short8*)(prow + j0) = o;               // full-row write: zero fill needed by pv
}

// ---------- PV GEMM, 128^2 core, causal K-cap. 512 = 8*64 XCD ----------
__global__ __launch_bounds__(256, 2) void pv128_kernel(
    const u16* __restrict__ P, const u16* __restrict__ vT,
    const int* __restrict__ lengths, float* __restrict__ out)
{
  extern __shared__ char lds[];
  const int bid = blockIdx.x;
  const int wg = (bid & 7) * 64 + (bid >> 3);
  const int b = wg >> 7;            // 128 tiles per batch
  const int rem = wg & 127;
  const int ty = rem >> 3;          // 16 q-row tiles
  const int xt = rem & 7;           // 8 d-col tiles
  const int len = lengths[b];
  const int kend = min(ty * 128 + 128, len);
  const int NT = (kend + 63) >> 6;  // >= 1 since len >= 1

  f32x4 acc[4][4];
#pragma unroll
  for (int i = 0; i < 4; ++i)
#pragma unroll
    for (int j = 0; j < 4; ++j) acc[i][j] = (f32x4){0.f,0.f,0.f,0.f};
  const u16* Ap = P  + ((size_t)b*S_ + (size_t)ty*128) * S_;
  const u16* Bv = vT + ((size_t)b*D_ + (size_t)xt*128) * S_;
  gemm128_core(Ap, S_, Bv, S_, NT, lds, acc);

  const int tid = threadIdx.x, w = tid >> 6, l = tid & 63;
  const int wm = w >> 1, wn = w & 1;
  const int fr = l & 15, kq = l >> 4;
  const int orow0 = ty*128 + wm*64 + kq*4;
  const int ocol0 = xt*128 + wn*64 + fr;
  float* ob = out + (size_t)b*S_*D_;
#pragma unroll
  for (int mf = 0; mf < 4; ++mf)
#pragma unroll
    for (int nf = 0; nf < 4; ++nf)
#pragma unroll
      for (int r2 = 0; r2 < 4; ++r2)
        ob[(size_t)(orow0 + mf*16 + r2)*D_ + (ocol0 + nf*16)] = acc[mf][nf][r2];
}

// ---------- launch ----------
extern "C" void kernel_launch(void* const* d_in, const int* in_sizes, int n_in,
                              void* d_out, int out_size, void* d_ws, size_t ws_size,
                              hipStream_t stream)
{
  const float* query = (const float*)d_in[0];
  const float* key_  = (const float*)d_in[1];
  const float* value = (const float*)d_in[2];
  const float* Wq = (const float*)d_in[3];
  const float* bq = (const float*)d_in[4];
  const float* Wk = (const float*)d_in[5];
  const float* bk = (const float*)d_in[6];
  const float* Wv = (const float*)d_in[7];
  const float* bv = (const float*)d_in[8];
  const void*  pmask = d_in[9];
  float* out = (float*)d_out;
  char* ws = (char*)d_ws;

  (void)hipFuncSetAttribute((const void*)proj256_kernel,
                            hipFuncAttributeMaxDynamicSharedMemorySize, 131072);
  (void)hipFuncSetAttribute((const void*)qk128_kernel,
                            hipFuncAttributeMaxDynamicSharedMemorySize, 65536);
  (void)hipFuncSetAttribute((const void*)pv128_kernel,
                            hipFuncAttributeMaxDynamicSharedMemorySize, 65536);

  // workspace layout (bytes):
  //   [0,16)                 lengths (int[4])
  //   [256, +50331648)       q,k bf16 [8192][1024] + vT bf16 [4][1024][2048]
  //   [50331904, +33554432)  P bf16 [4][2048][2048] (also v-normal pre-softmax)
  //   [83886336, +67108864)  union: {X bf16 + W bf16} then scores fp32
  int* lengths = (int*)ws;
  u16* q   = (u16*)(ws + 256);
  u16* kk  = q  + (size_t)MFLAT * D_;
  u16* vT  = kk + (size_t)MFLAT * D_;
  u16* Pbuf = (u16*)(ws + 50331904ull);
  u16* vbuf = Pbuf;
  char* scratch = ws + 83886336ull;
  u16* Xb = (u16*)scratch;
  u16* Wb = Xb + 3ull * MFLAT * E_;
  float* scores = (float*)scratch;

  cvt3_kernel<<<dim3(2048), 256, 0, stream>>>(query, key_, value, Xb, (MFLAT*E_)/4);
  cvt3_kernel<<<dim3(512),  256, 0, stream>>>(Wq, Wk, Wv, Wb, (D_*E_)/4);
  lengths_kernel<<<dim3(1), 256, 0, stream>>>(pmask, lengths);

  proj256_kernel<<<dim3(384), 512, 131072, stream>>>(Xb, Wb, bq, bk, bv, q, kk, vbuf);

  transpose_kernel<<<dim3(16, 32, 4), 256, 0, stream>>>(vbuf, vT);

  // QK^T: 544 blocks (4 b x 136 triangle 128-tiles), 2 blocks/CU
  qk128_kernel<<<dim3(544), 256, 65536, stream>>>(q, kk, lengths, scores);

  softmax_kernel<<<dim3(2048, 4), 256, 0, stream>>>(scores, lengths, Pbuf);

  // PV: 512 blocks (4 b x 16 ty x 8 xt), 2 blocks/CU
  pv128_kernel<<<dim3(512), 256, 65536, stream>>>(Pbuf, vT, lengths, out);
}